// Round 1
// baseline (1997.674 us; speedup 1.0000x reference)
//
#include <hip/hip_runtime.h>
#include <math.h>

// Problem constants
#define Bb 64
#define Nn 1024
#define FDd 768
#define Dd 256
#define KSs 8
#define TSs 12
#define Hh 4
#define HDd 64

// ---------------- block reduction helper (block = 256 threads) ----------------
__device__ __forceinline__ float blockSum256(float v, float* red) {
    #pragma unroll
    for (int o = 32; o > 0; o >>= 1) v += __shfl_down(v, o);
    int lane = threadIdx.x & 63, w = threadIdx.x >> 6;
    __syncthreads();
    if (lane == 0) red[w] = v;
    __syncthreads();
    return red[0] + red[1] + red[2] + red[3];
}

// ---------------- generic tiled f32 GEMM: C = A[MxK] @ W[KxN] + bias ----------------
// tiles 64x64, BK=16, 256 threads, 4x4 micro-tile. M,N mult of 64; K mult of 16.
__global__ __launch_bounds__(256) void gemm_bias(const float* __restrict__ A,
    const float* __restrict__ W, const float* __restrict__ bias,
    float* __restrict__ C, int M, int N, int K)
{
    __shared__ float As[16][64];   // [k][m]
    __shared__ float Bs[16][64];   // [k][n]
    const int t  = threadIdx.x;
    const int tx = t & 15, ty = t >> 4;
    const int n0 = blockIdx.x * 64, m0 = blockIdx.y * 64;
    const int ra = t >> 2, ca = (t & 3) * 4;
    const int rb = t >> 4, cb = (t & 15) * 4;
    float acc[4][4] = {};
    for (int k0 = 0; k0 < K; k0 += 16) {
        float4 av = *(const float4*)(A + (m0 + ra) * K + k0 + ca);
        As[ca + 0][ra] = av.x; As[ca + 1][ra] = av.y;
        As[ca + 2][ra] = av.z; As[ca + 3][ra] = av.w;
        *(float4*)&Bs[rb][cb] = *(const float4*)(W + (k0 + rb) * N + n0 + cb);
        __syncthreads();
        #pragma unroll
        for (int kk = 0; kk < 16; kk++) {
            float4 a4 = *(const float4*)&As[kk][ty * 4];
            float4 b4 = *(const float4*)&Bs[kk][tx * 4];
            acc[0][0] += a4.x * b4.x; acc[0][1] += a4.x * b4.y; acc[0][2] += a4.x * b4.z; acc[0][3] += a4.x * b4.w;
            acc[1][0] += a4.y * b4.x; acc[1][1] += a4.y * b4.y; acc[1][2] += a4.y * b4.z; acc[1][3] += a4.y * b4.w;
            acc[2][0] += a4.z * b4.x; acc[2][1] += a4.z * b4.y; acc[2][2] += a4.z * b4.z; acc[2][3] += a4.z * b4.w;
            acc[3][0] += a4.w * b4.x; acc[3][1] += a4.w * b4.y; acc[3][2] += a4.w * b4.z; acc[3][3] += a4.w * b4.w;
        }
        __syncthreads();
    }
    float4 bv = make_float4(0.f, 0.f, 0.f, 0.f);
    if (bias) bv = *(const float4*)(bias + n0 + tx * 4);
    #pragma unroll
    for (int i = 0; i < 4; i++) {
        float4 o;
        o.x = acc[i][0] + bv.x; o.y = acc[i][1] + bv.y;
        o.z = acc[i][2] + bv.z; o.w = acc[i][3] + bv.w;
        *(float4*)(C + (m0 + ty * 4 + i) * N + n0 + tx * 4) = o;
    }
}

// ---------------- LayerNorm (rows of 256), one block per row ----------------
__global__ __launch_bounds__(256) void ln_kernel(const float* __restrict__ in,
    const float* __restrict__ g, const float* __restrict__ b, float* __restrict__ out)
{
    __shared__ float red[4];
    int row = blockIdx.x, t = threadIdx.x;
    float x = in[row * Dd + t];
    float m = blockSum256(x, red) * (1.f / Dd);
    float d = x - m;
    float v = blockSum256(d * d, red) * (1.f / Dd);
    out[row * Dd + t] = d * (1.f / sqrtf(v + 1e-5f)) * g[t] + b[t];
}

// double LN in-place: buf = LN(LN(buf, g1,b1), g2,b2)
__global__ __launch_bounds__(256) void ln2_kernel(float* __restrict__ buf,
    const float* __restrict__ g1, const float* __restrict__ b1,
    const float* __restrict__ g2, const float* __restrict__ b2)
{
    __shared__ float red[4];
    int row = blockIdx.x, t = threadIdx.x;
    float x = buf[row * Dd + t];
    float m = blockSum256(x, red) * (1.f / Dd);
    float d = x - m;
    float v = blockSum256(d * d, red) * (1.f / Dd);
    float y = d * (1.f / sqrtf(v + 1e-5f)) * g1[t] + b1[t];
    float m2 = blockSum256(y, red) * (1.f / Dd);
    float d2 = y - m2;
    float v2 = blockSum256(d2 * d2, red) * (1.f / Dd);
    buf[row * Dd + t] = d2 * (1.f / sqrtf(v2 + 1e-5f)) * g2[t] + b2[t];
}

// ---------------- slots = mu + exp(log_sigma) * eps ----------------
__global__ void slots_init(const float* __restrict__ mu, const float* __restrict__ ls,
    const float* __restrict__ eps, float* __restrict__ slots)
{
    int idx = blockIdx.x * 256 + threadIdx.x;           // 64*12*256 total
    int md = idx % (TSs * Dd);
    slots[idx] = mu[md] + expf(ls[md]) * eps[idx];
}

// ---------------- dots[b,i,h,j] = (q[b,i,h,:] . k[b,j,h,:]) * 0.125 ----------------
// grid = B*H*4 (j-chunks of 256); 256 threads; per-lane k-row in VGPRs, q via uniform loads
__global__ __launch_bounds__(256) void dots_kernel(const float* __restrict__ qb,
    const float* __restrict__ kb, float* __restrict__ dots)
{
    int bid = blockIdx.x;
    int chunk = bid & 3, h = (bid >> 2) & 3, b = bid >> 4;
    int t = threadIdx.x, w = t >> 6, lane = t & 63;
    int j = chunk * 256 + w * 64 + lane;
    const float4* krow = (const float4*)(kb + (b * Nn + j) * Dd + h * HDd);
    float4 kr[16];
    #pragma unroll
    for (int c = 0; c < 16; c++) kr[c] = krow[c];
    const float* qbase = qb + b * TSs * Dd + h * HDd;
    #pragma unroll
    for (int i = 0; i < TSs; i++) {
        const float4* qrow = (const float4*)(qbase + i * Dd);
        float acc = 0.f;
        #pragma unroll
        for (int c = 0; c < 16; c++) {
            float4 q4 = qrow[c];
            acc += kr[c].x * q4.x + kr[c].y * q4.y + kr[c].z * q4.z + kr[c].w * q4.w;
        }
        dots[(b * 48 + i * 4 + h) * Nn + j] = acc * 0.125f;
    }
}

// ---------------- softmax over the 48 (i,h) entries per (b,j), in place ----------------
__global__ __launch_bounds__(256) void softmax48(float* __restrict__ dots)
{
    int b = blockIdx.x >> 2;
    int j = (blockIdx.x & 3) * 256 + threadIdx.x;
    float a[48];
    float m = -1e30f;
    #pragma unroll
    for (int idx = 0; idx < 48; idx++) { a[idx] = dots[(b * 48 + idx) * Nn + j]; m = fmaxf(m, a[idx]); }
    float s = 0.f;
    #pragma unroll
    for (int idx = 0; idx < 48; idx++) { a[idx] = expf(a[idx] - m); s += a[idx]; }
    float inv = 1.f / s;
    #pragma unroll
    for (int idx = 0; idx < 48; idx++) dots[(b * 48 + idx) * Nn + j] = a[idx] * inv;
}

// ---------------- per-(b,i,h) row sums of attn over j ----------------
__global__ __launch_bounds__(256) void rowsum_kernel(const float* __restrict__ attn,
    float* __restrict__ rsum)
{
    int row = blockIdx.x * 4 + (threadIdx.x >> 6);       // 3072 rows
    int lane = threadIdx.x & 63;
    const float* p = attn + row * Nn;
    float s = 0.f;
    #pragma unroll
    for (int c = 0; c < 16; c++) s += p[lane + c * 64];
    #pragma unroll
    for (int o = 32; o > 0; o >>= 1) s += __shfl_down(s, o);
    if (lane == 0) rsum[row] = s;
}

// ---------------- updates[b,i,h,d] = sum_j (attn+1e-8)*v / (rowsum+1e-8) ----------------
// grid = B*H; 4 waves split j; LDS cross-wave reduce. Deterministic, no atomics.
__global__ __launch_bounds__(256) void updates_kernel(const float* __restrict__ attn,
    const float* __restrict__ rsum, const float* __restrict__ vb, float* __restrict__ upd)
{
    int b = blockIdx.x >> 2, h = blockIdx.x & 3;
    int t = threadIdx.x, w = t >> 6, lane = t & 63;
    float acc[12] = {};
    float accv = 0.f;
    for (int j = w; j < Nn; j += 4) {
        float vv = vb[(b * Nn + j) * Dd + h * HDd + lane];
        accv += vv;
        #pragma unroll
        for (int i = 0; i < 12; i++)
            acc[i] += attn[(b * 48 + i * 4 + h) * Nn + j] * vv;
    }
    __shared__ float red[4][13][64];
    #pragma unroll
    for (int i = 0; i < 12; i++) red[w][i][lane] = acc[i];
    red[w][12][lane] = accv;
    __syncthreads();
    if (w == 0) {
        float sv = red[0][12][lane] + red[1][12][lane] + red[2][12][lane] + red[3][12][lane];
        #pragma unroll
        for (int i = 0; i < 12; i++) {
            float s = red[0][i][lane] + red[1][i][lane] + red[2][i][lane] + red[3][i][lane];
            float rs = rsum[b * 48 + i * 4 + h];
            upd[(b * TSs + i) * Dd + h * HDd + lane] = (s + 1e-8f * sv) / (rs + 1e-8f);
        }
    }
}

// ---------------- GRU gate combine, slots updated in place ----------------
__global__ __launch_bounds__(256) void gru_gate(const float* __restrict__ gx,
    const float* __restrict__ gh, float* __restrict__ slots)
{
    int idx = blockIdx.x * 256 + threadIdx.x;            // 768*256
    int row = idx >> 8, col = idx & 255;
    int base = row * 768 + col;
    float xr = gx[base], xz = gx[base + 256], xnv = gx[base + 512];
    float hr = gh[base], hz = gh[base + 256], hn = gh[base + 512];
    float r = 1.f / (1.f + expf(-(xr + hr)));
    float z = 1.f / (1.f + expf(-(xz + hz)));
    float nv = tanhf(xnv + r * hn);
    float hp = slots[idx];
    slots[idx] = (1.f - z) * nv + z * hp;
}

// ---------------- exact GELU in place ----------------
__global__ void gelu_kernel(float* __restrict__ x, int n)
{
    int i = blockIdx.x * 256 + threadIdx.x;
    if (i < n) { float v = x[i]; x[i] = 0.5f * v * (1.f + erff(v * 0.70710678118654752f)); }
}

// ---------------- a += b ----------------
__global__ void add_kernel(float* __restrict__ a, const float* __restrict__ b, int n)
{
    int i = blockIdx.x * 256 + threadIdx.x;
    if (i < n) a[i] += b[i];
}

__global__ void copy_kernel(float* __restrict__ o, const float* __restrict__ a, int n)
{
    int i = blockIdx.x * 256 + threadIdx.x;
    if (i < n) o[i] = a[i];
}

// ---------------- selection head + masked x write; one block per batch ----------------
__global__ __launch_bounds__(256) void select_kernel(const float* __restrict__ slots,
    const float* __restrict__ w1, const float* __restrict__ b1,
    const float* __restrict__ w2, const float* __restrict__ b2,
    float* __restrict__ dec, float* __restrict__ xout)
{
    int b = blockIdx.x, t = threadIdx.x;
    __shared__ float t1[8][128];
    __shared__ float lg[8][2];
    __shared__ float dsh[8];
    const float* obj = slots + b * TSs * Dd;             // rows 0..7 of this batch
    #pragma unroll
    for (int u = 0; u < 4; u++) {
        int idx = t + 256 * u;
        int k = idx >> 7, c = idx & 127;
        float s = b1[c];
        for (int d = 0; d < 256; d++) s += obj[k * 256 + d] * w1[d * 128 + c];
        t1[k][c] = fmaxf(s, 0.f);
    }
    __syncthreads();
    if (t < 16) {
        int k = t >> 1, o = t & 1;
        float s = b2[o];
        for (int c = 0; c < 128; c++) s += t1[k][c] * w2[c * 2 + o];
        lg[k][o] = s;
    }
    __syncthreads();
    if (t == 0) {
        float dv[8]; float sum = 0.f;
        for (int k = 0; k < 8; k++) { dv[k] = (lg[k][1] > lg[k][0]) ? 1.f : 0.f; sum += dv[k]; }
        float needed = fmaxf(2.f - sum, 0.f);
        float rank = 0.f;
        for (int k = 0; k < 8; k++) {
            float inact = 1.f - dv[k];
            rank += inact;
            if (inact > 0.f && rank <= needed) dv[k] = 1.f;
            dsh[k] = dv[k];
            dec[b * 8 + k] = dv[k];
        }
    }
    __syncthreads();
    for (int idx = t; idx < 2048; idx += 256) {
        int k = idx >> 8, c = idx & 255;
        xout[(b * 8 + k) * 256 + c] = obj[k * 256 + c] * dsh[k];
    }
}

// ---------------- GAT attention + residual (y = x + out), in place on xb ----------------
__global__ __launch_bounds__(256) void gat_attn(float* __restrict__ xb,
    const float* __restrict__ hmat, const float* __restrict__ av,
    const float* __restrict__ dec)
{
    int b = blockIdx.x, t = threadIdx.x;
    __shared__ float hs[8][256], xs[8][256];
    __shared__ float ei[8][4], ej[8][4], al[8][4][8], ds[8];
    for (int idx = t; idx < 2048; idx += 256) {
        int k = idx >> 8, c = idx & 255;
        hs[k][c] = hmat[(b * 8 + k) * 256 + c];
        xs[k][c] = xb[(b * 8 + k) * 256 + c];
    }
    if (t < 8) ds[t] = dec[b * 8 + t];
    __syncthreads();
    if (t < 32) {
        int k = t >> 2, h = t & 3;
        float s1 = 0.f, s2 = 0.f;
        for (int d = 0; d < 64; d++) {
            float hv = hs[k][h * 64 + d];
            s1 += hv * av[h * 128 + d];
            s2 += hv * av[h * 128 + 64 + d];
        }
        ei[k][h] = s1; ej[k][h] = s2;
    }
    __syncthreads();
    {
        int k = t >> 5, h = (t >> 3) & 3, n = t & 7;
        float e = ei[k][h] + ej[n][h];
        e = (e >= 0.f) ? e : 0.2f * e;
        if (ds[k] * ds[n] == 0.f) e = -1e9f;
        float mx = e;
        #pragma unroll
        for (int o = 4; o > 0; o >>= 1) mx = fmaxf(mx, __shfl_xor(mx, o, 8));
        float ex = expf(e - mx);
        float sm = ex;
        #pragma unroll
        for (int o = 4; o > 0; o >>= 1) sm += __shfl_xor(sm, o, 8);
        al[k][h][n] = ex / sm;
    }
    __syncthreads();
    int h = t >> 6, d = t & 63;
    for (int k = 0; k < 8; k++) {
        float o = 0.f;
        #pragma unroll
        for (int n = 0; n < 8; n++) o += al[k][h][n] * hs[n][h * 64 + d];
        xb[(b * 8 + k) * 256 + h * 64 + d] = xs[k][h * 64 + d] + o;
    }
}

// ======================================================================
extern "C" void kernel_launch(void* const* d_in, const int* in_sizes, int n_in,
                              void* d_out, int out_size, void* d_ws, size_t ws_size,
                              hipStream_t stream)
{
    (void)in_sizes; (void)n_in; (void)out_size; (void)ws_size;
    const float* features       = (const float*)d_in[0];
    const float* eps_noise      = (const float*)d_in[1];
    const float* in_w           = (const float*)d_in[2];
    const float* in_b           = (const float*)d_in[3];
    const float* in_ln_g        = (const float*)d_in[4];
    const float* in_ln_b        = (const float*)d_in[5];
    const float* ni_g           = (const float*)d_in[6];
    const float* ni_b           = (const float*)d_in[7];
    const float* slot_mu        = (const float*)d_in[8];
    const float* slot_log_sigma = (const float*)d_in[9];
    const float* q_w            = (const float*)d_in[10];
    const float* k_w            = (const float*)d_in[11];
    const float* v_w            = (const float*)d_in[12];
    const float* gru_wih        = (const float*)d_in[13];
    const float* gru_whh        = (const float*)d_in[14];
    const float* gru_bih        = (const float*)d_in[15];
    const float* gru_bhh        = (const float*)d_in[16];
    const float* ns_g           = (const float*)d_in[17];
    const float* ns_b           = (const float*)d_in[18];
    const float* ffn_ln_g       = (const float*)d_in[19];
    const float* ffn_ln_b       = (const float*)d_in[20];
    const float* ffn_w1         = (const float*)d_in[21];
    const float* ffn_b1         = (const float*)d_in[22];
    const float* ffn_w2         = (const float*)d_in[23];
    const float* ffn_b2         = (const float*)d_in[24];
    const float* sel_w1         = (const float*)d_in[25];
    const float* sel_b1         = (const float*)d_in[26];
    const float* sel_w2         = (const float*)d_in[27];
    const float* sel_b2         = (const float*)d_in[28];
    const float* gat_W          = (const float*)d_in[29];
    const float* gat_a          = (const float*)d_in[30];
    const float* gat_ln_g       = (const float*)d_in[31];
    const float* gat_ln_b       = (const float*)d_in[32];
    const float* gat_fln_g      = (const float*)d_in[33];
    const float* gat_fln_b      = (const float*)d_in[34];
    const float* gat_fw1        = (const float*)d_in[35];
    const float* gat_fb1        = (const float*)d_in[36];
    const float* gat_fw2        = (const float*)d_in[37];
    const float* gat_fb2        = (const float*)d_in[38];

    // ---- workspace layout (floats). Total = 3 * 16,777,216 = 201.3 MB ----
    float* ws = (float*)d_ws;
    float* kb = ws;                       // 65536*256
    float* vb = kb + 16777216;            // 65536*256
    float* xn = vb + 16777216;            // 65536*256  (dead after k/v GEMMs)
    // iteration-phase buffers aliased into the xn region (xn dead by then):
    float* attn  = xn;                    // 64*48*1024 = 3,145,728 (dots -> attn, in place)
    float* rsum  = attn + 3145728;        // 3072
    float* slots = rsum + 3072;           // 768*256
    float* sn    = slots + 196608;        // 768*256
    float* qbuf  = sn + 196608;           // 768*256
    float* upd   = qbuf + 196608;         // 768*256
    float* gx    = upd + 196608;          // 768*768
    float* gh    = gx + 589824;           // 768*768
    float* h1    = gx;                    // 768*1024 (aliases gx+gh, both dead)
    float* h2    = gx + 786432;           // 768*256  (aliases gh tail, dead)
    float* xb    = gh + 589824;           // 512*256
    float* hm    = xb + 131072;           // 512*256
    float* dec   = hm + 131072;           // 512

    dim3 blk(256);

    // 1) xn = features @ in_w + in_b ; then xn = LN(LN(xn))
    gemm_bias<<<dim3(Dd / 64, (Bb * Nn) / 64), blk, 0, stream>>>(features, in_w, in_b, xn, Bb * Nn, Dd, FDd);
    ln2_kernel<<<Bb * Nn, blk, 0, stream>>>(xn, in_ln_g, in_ln_b, ni_g, ni_b);

    // 2) k, v projections
    gemm_bias<<<dim3(4, 1024), blk, 0, stream>>>(xn, k_w, nullptr, kb, Bb * Nn, Dd, Dd);
    gemm_bias<<<dim3(4, 1024), blk, 0, stream>>>(xn, v_w, nullptr, vb, Bb * Nn, Dd, Dd);

    // 3) slots init
    slots_init<<<768, blk, 0, stream>>>(slot_mu, slot_log_sigma, eps_noise, slots);

    // 4) slot-attention iterations
    for (int it = 0; it < 3; it++) {
        ln_kernel<<<768, blk, 0, stream>>>(slots, ns_g, ns_b, sn);
        gemm_bias<<<dim3(4, 12), blk, 0, stream>>>(sn, q_w, nullptr, qbuf, 768, Dd, Dd);
        dots_kernel<<<Bb * Hh * 4, blk, 0, stream>>>(qbuf, kb, attn);
        softmax48<<<Bb * 4, blk, 0, stream>>>(attn);
        rowsum_kernel<<<768, blk, 0, stream>>>(attn, rsum);
        updates_kernel<<<Bb * Hh, blk, 0, stream>>>(attn, rsum, vb, upd);
        gemm_bias<<<dim3(12, 12), blk, 0, stream>>>(upd, gru_wih, gru_bih, gx, 768, 768, Dd);
        gemm_bias<<<dim3(12, 12), blk, 0, stream>>>(slots, gru_whh, gru_bhh, gh, 768, 768, Dd);
        gru_gate<<<768, blk, 0, stream>>>(gx, gh, slots);
        ln_kernel<<<768, blk, 0, stream>>>(slots, ffn_ln_g, ffn_ln_b, sn);
        gemm_bias<<<dim3(16, 12), blk, 0, stream>>>(sn, ffn_w1, ffn_b1, h1, 768, 1024, Dd);
        gelu_kernel<<<3072, blk, 0, stream>>>(h1, 768 * 1024);
        gemm_bias<<<dim3(4, 12), blk, 0, stream>>>(h1, ffn_w2, ffn_b2, h2, 768, Dd, 1024);
        add_kernel<<<768, blk, 0, stream>>>(slots, h2, 768 * 256);
    }

    // 5) selection + masked x
    select_kernel<<<Bb, blk, 0, stream>>>(slots, sel_w1, sel_b1, sel_w2, sel_b2, dec, xb);

    // 6) GAT layers
    for (int l = 0; l < 2; l++) {
        ln_kernel<<<512, blk, 0, stream>>>(xb, gat_ln_g + l * 256, gat_ln_b + l * 256, sn);
        gemm_bias<<<dim3(4, 8), blk, 0, stream>>>(sn, gat_W + l * 65536, nullptr, hm, 512, Dd, Dd);
        gat_attn<<<Bb, blk, 0, stream>>>(xb, hm, gat_a + l * 512, dec);
        ln_kernel<<<512, blk, 0, stream>>>(xb, gat_fln_g + l * 256, gat_fln_b + l * 256, sn);
        gemm_bias<<<dim3(16, 8), blk, 0, stream>>>(sn, gat_fw1 + l * 262144, gat_fb1 + l * 1024, h1, 512, 1024, Dd);
        gelu_kernel<<<2048, blk, 0, stream>>>(h1, 512 * 1024);
        gemm_bias<<<dim3(4, 8), blk, 0, stream>>>(h1, gat_fw2 + l * 262144, gat_fb2 + l * 256, h2, 512, Dd, 1024);
        add_kernel<<<512, blk, 0, stream>>>(xb, h2, 512 * 256);
    }

    // 7) output
    copy_kernel<<<512, blk, 0, stream>>>((float*)d_out, xb, 131072);
}

// Round 2
// 1372.805 us; speedup vs baseline: 1.4552x; 1.4552x over previous
//
#include <hip/hip_runtime.h>
#include <math.h>

// Problem constants
#define Bb 64
#define Nn 1024
#define FDd 768
#define Dd 256
#define KSs 8
#define TSs 12
#define Hh 4
#define HDd 64

typedef __attribute__((ext_vector_type(8))) short bf16x8;
typedef __attribute__((ext_vector_type(4))) float f32x4;

__device__ __forceinline__ ushort f2bf(float x) {
    union { float f; uint u; } v; v.f = x;
    uint r = v.u + 0x7FFFu + ((v.u >> 16) & 1u);   // RNE
    return (ushort)(r >> 16);
}
__device__ __forceinline__ float bf2f(ushort x) {
    union { uint u; float f; } v; v.u = ((uint)x) << 16;
    return v.f;
}
__device__ __forceinline__ uint pack2(float a, float b) {
    return (uint)f2bf(a) | ((uint)f2bf(b) << 16);
}

// ---------------- block reduction helper (block = 256 threads) ----------------
__device__ __forceinline__ float blockSum256(float v, float* red) {
    #pragma unroll
    for (int o = 32; o > 0; o >>= 1) v += __shfl_down(v, o);
    int lane = threadIdx.x & 63, w = threadIdx.x >> 6;
    __syncthreads();
    if (lane == 0) red[w] = v;
    __syncthreads();
    return red[0] + red[1] + red[2] + red[3];
}

// ============ bf16 MFMA GEMM: C[M][256] = A[M][K] @ W[K][256] + bias ============
// B given pre-transposed+bf16: WT[256][K]. Tile 128x256 (full N), BK=32,
// 256 threads = 4 waves (2x2), per-wave 64x128 = 4x8 frags of 16x16x32.
// A is f32 (converted during staging) or bf16 per template. C written bf16.
// LDS rows padded to 40 elems (80B) -> 2-way bank conflicts (free).
#define LPAD 40
template<bool A_F32>
__global__ __launch_bounds__(256) void gemm_mfma(const void* __restrict__ Ap,
    const ushort* __restrict__ WT, const float* __restrict__ bias,
    ushort* __restrict__ C, int M, int K)
{
    __shared__ __align__(16) ushort As[128 * LPAD];
    __shared__ __align__(16) ushort Bs[256 * LPAD];
    const int t = threadIdx.x;
    const int m0 = blockIdx.x * 128;
    const int lane = t & 63, wv = t >> 6;
    const int wr = wv >> 1, wc = wv & 1;
    const int lr = lane & 15, lk = lane >> 4;

    f32x4 acc[4][8] = {};

    // staging descriptors
    const float*  agf = (const float*)Ap  + (size_t)(m0 + (t >> 1)) * K + (t & 1) * 16;
    const ushort* agb0 = (const ushort*)Ap + (size_t)(m0 + (t >> 2)) * K + (t & 3) * 8;
    const ushort* agb1 = (const ushort*)Ap + (size_t)(m0 + 64 + (t >> 2)) * K + (t & 3) * 8;
    const ushort* bg  = WT + (size_t)(t >> 2) * K + (t & 3) * 8;

    for (int k0 = 0; k0 < K; k0 += 32) {
        // ---- stage A ----
        if (A_F32) {
            float4 f0 = *(const float4*)(agf + k0);
            float4 f1 = *(const float4*)(agf + k0 + 4);
            float4 f2 = *(const float4*)(agf + k0 + 8);
            float4 f3 = *(const float4*)(agf + k0 + 12);
            int4 w0, w1;
            w0.x = pack2(f0.x, f0.y); w0.y = pack2(f0.z, f0.w);
            w0.z = pack2(f1.x, f1.y); w0.w = pack2(f1.z, f1.w);
            w1.x = pack2(f2.x, f2.y); w1.y = pack2(f2.z, f2.w);
            w1.z = pack2(f3.x, f3.y); w1.w = pack2(f3.z, f3.w);
            int base = (t >> 1) * LPAD + (t & 1) * 16;
            *(int4*)&As[base]     = w0;
            *(int4*)&As[base + 8] = w1;
        } else {
            int4 a0 = *(const int4*)(agb0 + k0);
            int4 a1 = *(const int4*)(agb1 + k0);
            *(int4*)&As[(t >> 2) * LPAD + (t & 3) * 8]        = a0;
            *(int4*)&As[(64 + (t >> 2)) * LPAD + (t & 3) * 8] = a1;
        }
        // ---- stage B (full 256xBK slice of WT) ----
        #pragma unroll
        for (int p = 0; p < 4; p++) {
            int4 bvv = *(const int4*)(bg + (size_t)(p * 64) * K + k0);
            *(int4*)&Bs[(p * 64 + (t >> 2)) * LPAD + (t & 3) * 8] = bvv;
        }
        __syncthreads();
        // ---- fragments + MFMA ----
        bf16x8 af[4], bfr[8];
        #pragma unroll
        for (int mi = 0; mi < 4; mi++)
            af[mi] = *(const bf16x8*)&As[(wr * 64 + mi * 16 + lr) * LPAD + lk * 8];
        #pragma unroll
        for (int ni = 0; ni < 8; ni++)
            bfr[ni] = *(const bf16x8*)&Bs[(wc * 128 + ni * 16 + lr) * LPAD + lk * 8];
        #pragma unroll
        for (int mi = 0; mi < 4; mi++)
            #pragma unroll
            for (int ni = 0; ni < 8; ni++)
                acc[mi][ni] = __builtin_amdgcn_mfma_f32_16x16x32_bf16(af[mi], bfr[ni], acc[mi][ni], 0, 0, 0);
        __syncthreads();
    }
    // ---- epilogue: C/D layout col=lane&15, row=(lane>>4)*4+reg ----
    #pragma unroll
    for (int mi = 0; mi < 4; mi++) {
        int grow = m0 + wr * 64 + mi * 16 + lk * 4;
        #pragma unroll
        for (int ni = 0; ni < 8; ni++) {
            int col = wc * 128 + ni * 16 + lr;
            float bv = bias ? bias[col] : 0.f;
            #pragma unroll
            for (int r = 0; r < 4; r++)
                C[(size_t)(grow + r) * 256 + col] = f2bf(acc[mi][ni][r] + bv);
        }
    }
}

// ---------------- weight transpose+cast: wt[n][k] = bf16(w[k][n]) ----------------
__global__ void prep_wt(const float* __restrict__ w, ushort* __restrict__ wt, int K, int N)
{
    int idx = blockIdx.x * 256 + threadIdx.x;
    int n = idx / K, k = idx - n * K;
    wt[idx] = f2bf(w[k * N + n]);
}

// ---------------- generic tiled f32 GEMM (kept for small/medium matmuls) ----------------
__global__ __launch_bounds__(256) void gemm_bias(const float* __restrict__ A,
    const float* __restrict__ W, const float* __restrict__ bias,
    float* __restrict__ C, int M, int N, int K)
{
    __shared__ float As[16][64];
    __shared__ float Bs[16][64];
    const int t  = threadIdx.x;
    const int tx = t & 15, ty = t >> 4;
    const int n0 = blockIdx.x * 64, m0 = blockIdx.y * 64;
    const int ra = t >> 2, ca = (t & 3) * 4;
    const int rb = t >> 4, cb = (t & 15) * 4;
    float acc[4][4] = {};
    for (int k0 = 0; k0 < K; k0 += 16) {
        float4 av = *(const float4*)(A + (m0 + ra) * K + k0 + ca);
        As[ca + 0][ra] = av.x; As[ca + 1][ra] = av.y;
        As[ca + 2][ra] = av.z; As[ca + 3][ra] = av.w;
        *(float4*)&Bs[rb][cb] = *(const float4*)(W + (k0 + rb) * N + n0 + cb);
        __syncthreads();
        #pragma unroll
        for (int kk = 0; kk < 16; kk++) {
            float4 a4 = *(const float4*)&As[kk][ty * 4];
            float4 b4 = *(const float4*)&Bs[kk][tx * 4];
            acc[0][0] += a4.x * b4.x; acc[0][1] += a4.x * b4.y; acc[0][2] += a4.x * b4.z; acc[0][3] += a4.x * b4.w;
            acc[1][0] += a4.y * b4.x; acc[1][1] += a4.y * b4.y; acc[1][2] += a4.y * b4.z; acc[1][3] += a4.y * b4.w;
            acc[2][0] += a4.z * b4.x; acc[2][1] += a4.z * b4.y; acc[2][2] += a4.z * b4.z; acc[2][3] += a4.z * b4.w;
            acc[3][0] += a4.w * b4.x; acc[3][1] += a4.w * b4.y; acc[3][2] += a4.w * b4.z; acc[3][3] += a4.w * b4.w;
        }
        __syncthreads();
    }
    float4 bv = make_float4(0.f, 0.f, 0.f, 0.f);
    if (bias) bv = *(const float4*)(bias + n0 + tx * 4);
    #pragma unroll
    for (int i = 0; i < 4; i++) {
        float4 o;
        o.x = acc[i][0] + bv.x; o.y = acc[i][1] + bv.y;
        o.z = acc[i][2] + bv.z; o.w = acc[i][3] + bv.w;
        *(float4*)(C + (m0 + ty * 4 + i) * N + n0 + tx * 4) = o;
    }
}

// ---------------- LayerNorm f32 (rows of 256) ----------------
__global__ __launch_bounds__(256) void ln_kernel(const float* __restrict__ in,
    const float* __restrict__ g, const float* __restrict__ b, float* __restrict__ out)
{
    __shared__ float red[4];
    int row = blockIdx.x, t = threadIdx.x;
    float x = in[row * Dd + t];
    float m = blockSum256(x, red) * (1.f / Dd);
    float d = x - m;
    float v = blockSum256(d * d, red) * (1.f / Dd);
    out[row * Dd + t] = d * (1.f / sqrtf(v + 1e-5f)) * g[t] + b[t];
}

// double LN in-place on bf16 buffer (math in f32)
__global__ __launch_bounds__(256) void ln2b_kernel(ushort* __restrict__ buf,
    const float* __restrict__ g1, const float* __restrict__ b1,
    const float* __restrict__ g2, const float* __restrict__ b2)
{
    __shared__ float red[4];
    int row = blockIdx.x, t = threadIdx.x;
    float x = bf2f(buf[row * Dd + t]);
    float m = blockSum256(x, red) * (1.f / Dd);
    float d = x - m;
    float v = blockSum256(d * d, red) * (1.f / Dd);
    float y = d * (1.f / sqrtf(v + 1e-5f)) * g1[t] + b1[t];
    float m2 = blockSum256(y, red) * (1.f / Dd);
    float d2 = y - m2;
    float v2 = blockSum256(d2 * d2, red) * (1.f / Dd);
    buf[row * Dd + t] = f2bf(d2 * (1.f / sqrtf(v2 + 1e-5f)) * g2[t] + b2[t]);
}

// ---------------- slots = mu + exp(log_sigma) * eps ----------------
__global__ void slots_init(const float* __restrict__ mu, const float* __restrict__ ls,
    const float* __restrict__ eps, float* __restrict__ slots)
{
    int idx = blockIdx.x * 256 + threadIdx.x;
    int md = idx % (TSs * Dd);
    slots[idx] = mu[md] + expf(ls[md]) * eps[idx];
}

// ---------------- dots[b,i,h,j] = (q . k) * 0.125 ; k is bf16 ----------------
__global__ __launch_bounds__(256) void dots_kernel(const float* __restrict__ qb,
    const ushort* __restrict__ kb, float* __restrict__ dots)
{
    int bid = blockIdx.x;
    int chunk = bid & 3, h = (bid >> 2) & 3, b = bid >> 4;
    int t = threadIdx.x, w = t >> 6, lane = t & 63;
    int j = chunk * 256 + w * 64 + lane;
    const uint* kp = (const uint*)(kb + (size_t)(b * Nn + j) * Dd + h * HDd);
    float kr[64];
    #pragma unroll
    for (int c = 0; c < 8; c++) {
        int4 kv4 = *(const int4*)(kp + c * 4);
        uint u0 = (uint)kv4.x, u1 = (uint)kv4.y, u2 = (uint)kv4.z, u3 = (uint)kv4.w;
        kr[c * 8 + 0] = __uint_as_float(u0 << 16); kr[c * 8 + 1] = __uint_as_float(u0 & 0xffff0000u);
        kr[c * 8 + 2] = __uint_as_float(u1 << 16); kr[c * 8 + 3] = __uint_as_float(u1 & 0xffff0000u);
        kr[c * 8 + 4] = __uint_as_float(u2 << 16); kr[c * 8 + 5] = __uint_as_float(u2 & 0xffff0000u);
        kr[c * 8 + 6] = __uint_as_float(u3 << 16); kr[c * 8 + 7] = __uint_as_float(u3 & 0xffff0000u);
    }
    const float* qbase = qb + b * TSs * Dd + h * HDd;
    #pragma unroll
    for (int i = 0; i < TSs; i++) {
        const float* qrow = qbase + i * Dd;
        float acc = 0.f;
        #pragma unroll
        for (int c = 0; c < 64; c++) acc += kr[c] * qrow[c];
        dots[(b * 48 + i * 4 + h) * Nn + j] = acc * 0.125f;
    }
}

// ---------------- softmax over the 48 (i,h) entries per (b,j) ----------------
__global__ __launch_bounds__(256) void softmax48(float* __restrict__ dots)
{
    int b = blockIdx.x >> 2;
    int j = (blockIdx.x & 3) * 256 + threadIdx.x;
    float a[48];
    float m = -1e30f;
    #pragma unroll
    for (int idx = 0; idx < 48; idx++) { a[idx] = dots[(b * 48 + idx) * Nn + j]; m = fmaxf(m, a[idx]); }
    float s = 0.f;
    #pragma unroll
    for (int idx = 0; idx < 48; idx++) { a[idx] = expf(a[idx] - m); s += a[idx]; }
    float inv = 1.f / s;
    #pragma unroll
    for (int idx = 0; idx < 48; idx++) dots[(b * 48 + idx) * Nn + j] = a[idx] * inv;
}

// ---------------- per-(b,i,h) row sums of attn over j ----------------
__global__ __launch_bounds__(256) void rowsum_kernel(const float* __restrict__ attn,
    float* __restrict__ rsum)
{
    int row = blockIdx.x * 4 + (threadIdx.x >> 6);
    int lane = threadIdx.x & 63;
    const float* p = attn + (size_t)row * Nn;
    float s = 0.f;
    #pragma unroll
    for (int c = 0; c < 16; c++) s += p[lane + c * 64];
    #pragma unroll
    for (int o = 32; o > 0; o >>= 1) s += __shfl_down(s, o);
    if (lane == 0) rsum[row] = s;
}

// ---------------- updates: v is bf16 ----------------
__global__ __launch_bounds__(256) void updates_kernel(const float* __restrict__ attn,
    const float* __restrict__ rsum, const ushort* __restrict__ vb, float* __restrict__ upd)
{
    int b = blockIdx.x >> 2, h = blockIdx.x & 3;
    int t = threadIdx.x, w = t >> 6, lane = t & 63;
    float acc[12] = {};
    float accv = 0.f;
    for (int j = w; j < Nn; j += 4) {
        float vv = __uint_as_float(((uint)vb[(size_t)(b * Nn + j) * Dd + h * HDd + lane]) << 16);
        accv += vv;
        #pragma unroll
        for (int i = 0; i < 12; i++)
            acc[i] += attn[(b * 48 + i * 4 + h) * Nn + j] * vv;
    }
    __shared__ float red[4][13][64];
    #pragma unroll
    for (int i = 0; i < 12; i++) red[w][i][lane] = acc[i];
    red[w][12][lane] = accv;
    __syncthreads();
    if (w == 0) {
        float sv = red[0][12][lane] + red[1][12][lane] + red[2][12][lane] + red[3][12][lane];
        #pragma unroll
        for (int i = 0; i < 12; i++) {
            float s = red[0][i][lane] + red[1][i][lane] + red[2][i][lane] + red[3][i][lane];
            float rs = rsum[b * 48 + i * 4 + h];
            upd[(b * TSs + i) * Dd + h * HDd + lane] = (s + 1e-8f * sv) / (rs + 1e-8f);
        }
    }
}

// ---------------- GRU gate combine ----------------
__global__ __launch_bounds__(256) void gru_gate(const float* __restrict__ gx,
    const float* __restrict__ gh, float* __restrict__ slots)
{
    int idx = blockIdx.x * 256 + threadIdx.x;
    int row = idx >> 8, col = idx & 255;
    int base = row * 768 + col;
    float xr = gx[base], xz = gx[base + 256], xnv = gx[base + 512];
    float hr = gh[base], hz = gh[base + 256], hn = gh[base + 512];
    float r = 1.f / (1.f + expf(-(xr + hr)));
    float z = 1.f / (1.f + expf(-(xz + hz)));
    float nv = tanhf(xnv + r * hn);
    float hp = slots[idx];
    slots[idx] = (1.f - z) * nv + z * hp;
}

__global__ void gelu_kernel(float* __restrict__ x, int n)
{
    int i = blockIdx.x * 256 + threadIdx.x;
    if (i < n) { float v = x[i]; x[i] = 0.5f * v * (1.f + erff(v * 0.70710678118654752f)); }
}

__global__ void add_kernel(float* __restrict__ a, const float* __restrict__ b, int n)
{
    int i = blockIdx.x * 256 + threadIdx.x;
    if (i < n) a[i] += b[i];
}

__global__ void add_out_kernel(float* __restrict__ o, const float* __restrict__ a,
    const float* __restrict__ b, int n)
{
    int i = blockIdx.x * 256 + threadIdx.x;
    if (i < n) o[i] = a[i] + b[i];
}

// ---------------- selection head + masked x write ----------------
__global__ __launch_bounds__(256) void select_kernel(const float* __restrict__ slots,
    const float* __restrict__ w1, const float* __restrict__ b1,
    const float* __restrict__ w2, const float* __restrict__ b2,
    float* __restrict__ dec, float* __restrict__ xout)
{
    int b = blockIdx.x, t = threadIdx.x;
    __shared__ float t1[8][128];
    __shared__ float lg[8][2];
    __shared__ float dsh[8];
    const float* obj = slots + b * TSs * Dd;
    #pragma unroll
    for (int u = 0; u < 4; u++) {
        int idx = t + 256 * u;
        int k = idx >> 7, c = idx & 127;
        float s = b1[c];
        for (int d = 0; d < 256; d++) s += obj[k * 256 + d] * w1[d * 128 + c];
        t1[k][c] = fmaxf(s, 0.f);
    }
    __syncthreads();
    if (t < 16) {
        int k = t >> 1, o = t & 1;
        float s = b2[o];
        for (int c = 0; c < 128; c++) s += t1[k][c] * w2[c * 2 + o];
        lg[k][o] = s;
    }
    __syncthreads();
    if (t == 0) {
        float dv[8]; float sum = 0.f;
        for (int k = 0; k < 8; k++) { dv[k] = (lg[k][1] > lg[k][0]) ? 1.f : 0.f; sum += dv[k]; }
        float needed = fmaxf(2.f - sum, 0.f);
        float rank = 0.f;
        for (int k = 0; k < 8; k++) {
            float inact = 1.f - dv[k];
            rank += inact;
            if (inact > 0.f && rank <= needed) dv[k] = 1.f;
            dsh[k] = dv[k];
            dec[b * 8 + k] = dv[k];
        }
    }
    __syncthreads();
    for (int idx = t; idx < 2048; idx += 256) {
        int k = idx >> 8, c = idx & 255;
        xout[(b * 8 + k) * 256 + c] = obj[k * 256 + c] * dsh[k];
    }
}

// ---------------- GAT attention + residual ----------------
__global__ __launch_bounds__(256) void gat_attn(float* __restrict__ xb,
    const float* __restrict__ hmat, const float* __restrict__ av,
    const float* __restrict__ dec)
{
    int b = blockIdx.x, t = threadIdx.x;
    __shared__ float hs[8][256], xs[8][256];
    __shared__ float ei[8][4], ej[8][4], al[8][4][8], ds[8];
    for (int idx = t; idx < 2048; idx += 256) {
        int k = idx >> 8, c = idx & 255;
        hs[k][c] = hmat[(b * 8 + k) * 256 + c];
        xs[k][c] = xb[(b * 8 + k) * 256 + c];
    }
    if (t < 8) ds[t] = dec[b * 8 + t];
    __syncthreads();
    if (t < 32) {
        int k = t >> 2, h = t & 3;
        float s1 = 0.f, s2 = 0.f;
        for (int d = 0; d < 64; d++) {
            float hv = hs[k][h * 64 + d];
            s1 += hv * av[h * 128 + d];
            s2 += hv * av[h * 128 + 64 + d];
        }
        ei[k][h] = s1; ej[k][h] = s2;
    }
    __syncthreads();
    {
        int k = t >> 5, h = (t >> 3) & 3, n = t & 7;
        float e = ei[k][h] + ej[n][h];
        e = (e >= 0.f) ? e : 0.2f * e;
        if (ds[k] * ds[n] == 0.f) e = -1e9f;
        float mx = e;
        #pragma unroll
        for (int o = 4; o > 0; o >>= 1) mx = fmaxf(mx, __shfl_xor(mx, o, 8));
        float ex = expf(e - mx);
        float sm = ex;
        #pragma unroll
        for (int o = 4; o > 0; o >>= 1) sm += __shfl_xor(sm, o, 8);
        al[k][h][n] = ex / sm;
    }
    __syncthreads();
    int h = t >> 6, d = t & 63;
    for (int k = 0; k < 8; k++) {
        float o = 0.f;
        #pragma unroll
        for (int n = 0; n < 8; n++) o += al[k][h][n] * hs[n][h * 64 + d];
        xb[(b * 8 + k) * 256 + h * 64 + d] = xs[k][h * 64 + d] + o;
    }
}

// ======================================================================
extern "C" void kernel_launch(void* const* d_in, const int* in_sizes, int n_in,
                              void* d_out, int out_size, void* d_ws, size_t ws_size,
                              hipStream_t stream)
{
    (void)in_sizes; (void)n_in; (void)out_size; (void)ws_size;
    const float* features       = (const float*)d_in[0];
    const float* eps_noise      = (const float*)d_in[1];
    const float* in_w           = (const float*)d_in[2];
    const float* in_b           = (const float*)d_in[3];
    const float* in_ln_g        = (const float*)d_in[4];
    const float* in_ln_b        = (const float*)d_in[5];
    const float* ni_g           = (const float*)d_in[6];
    const float* ni_b           = (const float*)d_in[7];
    const float* slot_mu        = (const float*)d_in[8];
    const float* slot_log_sigma = (const float*)d_in[9];
    const float* q_w            = (const float*)d_in[10];
    const float* k_w            = (const float*)d_in[11];
    const float* v_w            = (const float*)d_in[12];
    const float* gru_wih        = (const float*)d_in[13];
    const float* gru_whh        = (const float*)d_in[14];
    const float* gru_bih        = (const float*)d_in[15];
    const float* gru_bhh        = (const float*)d_in[16];
    const float* ns_g           = (const float*)d_in[17];
    const float* ns_b           = (const float*)d_in[18];
    const float* ffn_ln_g       = (const float*)d_in[19];
    const float* ffn_ln_b       = (const float*)d_in[20];
    const float* ffn_w1         = (const float*)d_in[21];
    const float* ffn_b1         = (const float*)d_in[22];
    const float* ffn_w2         = (const float*)d_in[23];
    const float* ffn_b2         = (const float*)d_in[24];
    const float* sel_w1         = (const float*)d_in[25];
    const float* sel_b1         = (const float*)d_in[26];
    const float* sel_w2         = (const float*)d_in[27];
    const float* sel_b2         = (const float*)d_in[28];
    const float* gat_W          = (const float*)d_in[29];
    const float* gat_a          = (const float*)d_in[30];
    const float* gat_ln_g       = (const float*)d_in[31];
    const float* gat_ln_b       = (const float*)d_in[32];
    const float* gat_fln_g      = (const float*)d_in[33];
    const float* gat_fln_b      = (const float*)d_in[34];
    const float* gat_fw1        = (const float*)d_in[35];
    const float* gat_fb1        = (const float*)d_in[36];
    const float* gat_fw2        = (const float*)d_in[37];
    const float* gat_fb2        = (const float*)d_in[38];

    // ---- workspace layout: bf16 region then f32 region (~124 MB total) ----
    ushort* kb  = (ushort*)d_ws;          // 16,777,216 bf16
    ushort* vb  = kb + 16777216;
    ushort* xnb = vb + 16777216;
    ushort* wtb = xnb + 16777216;         // in_w^T(196608) + k_w^T(65536) + v_w^T(65536)
    float* fbase = (float*)(wtb + 393216);
    float* attn  = fbase;                 // 3,145,728
    float* rsum  = attn + 3145728;        // 3072 (pad 4096)
    float* slots = rsum + 4096;           // 196608
    float* sn    = slots + 196608;
    float* qbuf  = sn + 196608;
    float* upd   = qbuf + 196608;
    float* gx    = upd + 196608;          // 589824
    float* gh    = gx + 589824;           // 589824
    float* h1    = gx;                    // 786432 (aliases gx+gh when dead)
    float* h2    = gx + 786432;           // 196608 (within gx+gh region)
    float* xb    = gh + 589824;           // 131072
    float* hm    = xb + 131072;           // 131072
    float* dec   = hm + 131072;           // 512

    dim3 blk(256);

    // 0) weights -> bf16 transposed
    prep_wt<<<768, blk, 0, stream>>>(in_w, wtb, 768, 256);
    prep_wt<<<256, blk, 0, stream>>>(k_w, wtb + 196608, 256, 256);
    prep_wt<<<256, blk, 0, stream>>>(v_w, wtb + 262144, 256, 256);

    // 1) xnb = bf16(features @ in_w + in_b); then double-LN in place
    gemm_mfma<true><<<512, blk, 0, stream>>>(features, wtb, in_b, xnb, Bb * Nn, FDd);
    ln2b_kernel<<<Bb * Nn, blk, 0, stream>>>(xnb, in_ln_g, in_ln_b, ni_g, ni_b);

    // 2) k, v projections (bf16 in, bf16 out)
    gemm_mfma<false><<<512, blk, 0, stream>>>(xnb, wtb + 196608, nullptr, kb, Bb * Nn, Dd);
    gemm_mfma<false><<<512, blk, 0, stream>>>(xnb, wtb + 262144, nullptr, vb, Bb * Nn, Dd);

    // 3) slots init
    slots_init<<<768, blk, 0, stream>>>(slot_mu, slot_log_sigma, eps_noise, slots);

    // 4) slot-attention iterations
    for (int it = 0; it < 3; it++) {
        ln_kernel<<<768, blk, 0, stream>>>(slots, ns_g, ns_b, sn);
        gemm_bias<<<dim3(4, 12), blk, 0, stream>>>(sn, q_w, nullptr, qbuf, 768, Dd, Dd);
        dots_kernel<<<Bb * Hh * 4, blk, 0, stream>>>(qbuf, kb, attn);
        softmax48<<<Bb * 4, blk, 0, stream>>>(attn);
        rowsum_kernel<<<768, blk, 0, stream>>>(attn, rsum);
        updates_kernel<<<Bb * Hh, blk, 0, stream>>>(attn, rsum, vb, upd);
        gemm_bias<<<dim3(12, 12), blk, 0, stream>>>(upd, gru_wih, gru_bih, gx, 768, 768, Dd);
        gemm_bias<<<dim3(12, 12), blk, 0, stream>>>(slots, gru_whh, gru_bhh, gh, 768, 768, Dd);
        gru_gate<<<768, blk, 0, stream>>>(gx, gh, slots);
        ln_kernel<<<768, blk, 0, stream>>>(slots, ffn_ln_g, ffn_ln_b, sn);
        gemm_bias<<<dim3(16, 12), blk, 0, stream>>>(sn, ffn_w1, ffn_b1, h1, 768, 1024, Dd);
        gelu_kernel<<<3072, blk, 0, stream>>>(h1, 768 * 1024);
        gemm_bias<<<dim3(4, 12), blk, 0, stream>>>(h1, ffn_w2, ffn_b2, h2, 768, Dd, 1024);
        add_kernel<<<768, blk, 0, stream>>>(slots, h2, 768 * 256);
    }

    // 5) selection + masked x
    select_kernel<<<Bb, blk, 0, stream>>>(slots, sel_w1, sel_b1, sel_w2, sel_b2, dec, xb);

    // 6) GAT layers
    for (int l = 0; l < 2; l++) {
        ln_kernel<<<512, blk, 0, stream>>>(xb, gat_ln_g + l * 256, gat_ln_b + l * 256, sn);
        gemm_bias<<<dim3(4, 8), blk, 0, stream>>>(sn, gat_W + l * 65536, nullptr, hm, 512, Dd, Dd);
        gat_attn<<<Bb, blk, 0, stream>>>(xb, hm, gat_a + l * 512, dec);
        ln_kernel<<<512, blk, 0, stream>>>(xb, gat_fln_g + l * 256, gat_fln_b + l * 256, sn);
        gemm_bias<<<dim3(16, 8), blk, 0, stream>>>(sn, gat_fw1 + l * 262144, gat_fb1 + l * 1024, h1, 512, 1024, Dd);
        gelu_kernel<<<2048, blk, 0, stream>>>(h1, 512 * 1024);
        gemm_bias<<<dim3(4, 8), blk, 0, stream>>>(h1, gat_fw2 + l * 262144, gat_fb2 + l * 256, h2, 512, Dd, 1024);
        if (l == 0)
            add_kernel<<<512, blk, 0, stream>>>(xb, h2, 512 * 256);
        else
            add_out_kernel<<<512, blk, 0, stream>>>((float*)d_out, xb, h2, 512 * 256);
    }
}

// Round 3
// 1001.557 us; speedup vs baseline: 1.9946x; 1.3707x over previous
//
#include <hip/hip_runtime.h>
#include <math.h>

// Problem constants
#define Bb 64
#define Nn 1024
#define FDd 768
#define Dd 256
#define KSs 8
#define TSs 12
#define Hh 4
#define HDd 64

typedef __attribute__((ext_vector_type(8))) short bf16x8;
typedef __attribute__((ext_vector_type(4))) float f32x4;

__device__ __forceinline__ ushort f2bf(float x) {
    union { float f; uint u; } v; v.f = x;
    uint r = v.u + 0x7FFFu + ((v.u >> 16) & 1u);   // RNE
    return (ushort)(r >> 16);
}
__device__ __forceinline__ float bf2f(ushort x) {
    union { uint u; float f; } v; v.u = ((uint)x) << 16;
    return v.f;
}
__device__ __forceinline__ uint pack2(float a, float b) {
    return (uint)f2bf(a) | ((uint)f2bf(b) << 16);
}
__device__ __forceinline__ float waveSum(float v) {
    #pragma unroll
    for (int o = 32; o > 0; o >>= 1) v += __shfl_xor(v, o);
    return v;
}

// ============ bf16 MFMA GEMM: C[M][N] = act(A[M][K] @ WT^T + bias) (+res) ============
// WT: bf16 [N][K]. Tile 128x256, BK=32, 256 thr = 4 waves (2x2), 16x16x32 MFMA.
// Pipelined: next K-step's global loads issue between ds_reads and MFMAs.
#define LPAD 40
template<bool A_F32, bool OUT_BF16, bool GELU_ACT, bool RES>
__global__ __launch_bounds__(256) void gemm_mfma(const void* __restrict__ Ap,
    const ushort* __restrict__ WT, const float* __restrict__ bias,
    void* __restrict__ Cp, const float* __restrict__ res, int M, int N, int K)
{
    __shared__ __align__(16) ushort As[128 * LPAD];
    __shared__ __align__(16) ushort Bs[256 * LPAD];
    const int t = threadIdx.x;
    const int m0 = blockIdx.x * 128, n0 = blockIdx.y * 256;
    const int lane = t & 63, wv = t >> 6;
    const int wr = wv >> 1, wc = wv & 1;
    const int lr = lane & 15, lk = lane >> 4;

    f32x4 acc[4][8] = {};

    const float*  agf  = (const float*)Ap  + (size_t)(m0 + (t >> 1)) * K + (t & 1) * 16;
    const ushort* agb0 = (const ushort*)Ap + (size_t)(m0 + (t >> 2)) * K + (t & 3) * 8;
    const ushort* agb1 = (const ushort*)Ap + (size_t)(m0 + 64 + (t >> 2)) * K + (t & 3) * 8;
    const ushort* bg   = WT + (size_t)(n0 + (t >> 2)) * K + (t & 3) * 8;

    float4 fA0, fA1, fA2, fA3; int4 iA0, iA1; int4 iB0, iB1, iB2, iB3;

#define GLOAD(k0) do { \
        if (A_F32) { \
            fA0 = *(const float4*)(agf + (k0));      fA1 = *(const float4*)(agf + (k0) + 4); \
            fA2 = *(const float4*)(agf + (k0) + 8);  fA3 = *(const float4*)(agf + (k0) + 12); \
        } else { \
            iA0 = *(const int4*)(agb0 + (k0)); iA1 = *(const int4*)(agb1 + (k0)); \
        } \
        iB0 = *(const int4*)(bg + (k0)); \
        iB1 = *(const int4*)(bg + (size_t)64  * K + (k0)); \
        iB2 = *(const int4*)(bg + (size_t)128 * K + (k0)); \
        iB3 = *(const int4*)(bg + (size_t)192 * K + (k0)); \
    } while (0)

#define LSTORE() do { \
        if (A_F32) { \
            int4 w0, w1; \
            w0.x = pack2(fA0.x, fA0.y); w0.y = pack2(fA0.z, fA0.w); \
            w0.z = pack2(fA1.x, fA1.y); w0.w = pack2(fA1.z, fA1.w); \
            w1.x = pack2(fA2.x, fA2.y); w1.y = pack2(fA2.z, fA2.w); \
            w1.z = pack2(fA3.x, fA3.y); w1.w = pack2(fA3.z, fA3.w); \
            int base = (t >> 1) * LPAD + (t & 1) * 16; \
            *(int4*)&As[base] = w0; *(int4*)&As[base + 8] = w1; \
        } else { \
            *(int4*)&As[(t >> 2) * LPAD + (t & 3) * 8]        = iA0; \
            *(int4*)&As[(64 + (t >> 2)) * LPAD + (t & 3) * 8] = iA1; \
        } \
        *(int4*)&Bs[(t >> 2) * LPAD + (t & 3) * 8]         = iB0; \
        *(int4*)&Bs[(64 + (t >> 2)) * LPAD + (t & 3) * 8]  = iB1; \
        *(int4*)&Bs[(128 + (t >> 2)) * LPAD + (t & 3) * 8] = iB2; \
        *(int4*)&Bs[(192 + (t >> 2)) * LPAD + (t & 3) * 8] = iB3; \
    } while (0)

    GLOAD(0);
    for (int k0 = 0; k0 < K; k0 += 32) {
        LSTORE();
        __syncthreads();
        bf16x8 af[4], bfr[8];
        #pragma unroll
        for (int mi = 0; mi < 4; mi++)
            af[mi] = *(const bf16x8*)&As[(wr * 64 + mi * 16 + lr) * LPAD + lk * 8];
        #pragma unroll
        for (int ni = 0; ni < 8; ni++)
            bfr[ni] = *(const bf16x8*)&Bs[(wc * 128 + ni * 16 + lr) * LPAD + lk * 8];
        if (k0 + 32 < K) GLOAD(k0 + 32);   // overlap with MFMAs below
        #pragma unroll
        for (int mi = 0; mi < 4; mi++)
            #pragma unroll
            for (int ni = 0; ni < 8; ni++)
                acc[mi][ni] = __builtin_amdgcn_mfma_f32_16x16x32_bf16(af[mi], bfr[ni], acc[mi][ni], 0, 0, 0);
        __syncthreads();
    }
#undef GLOAD
#undef LSTORE
    // epilogue: C/D layout col=lane&15, row=(lane>>4)*4+reg
    #pragma unroll
    for (int mi = 0; mi < 4; mi++) {
        int grow = m0 + wr * 64 + mi * 16 + lk * 4;
        #pragma unroll
        for (int ni = 0; ni < 8; ni++) {
            int gcol = n0 + wc * 128 + ni * 16 + lr;
            float bv = bias ? bias[gcol] : 0.f;
            #pragma unroll
            for (int r = 0; r < 4; r++) {
                float v = acc[mi][ni][r] + bv;
                if (GELU_ACT) v = 0.5f * v * (1.f + erff(v * 0.70710678118654752f));
                size_t idx = (size_t)(grow + r) * N + gcol;
                if (RES) v += res[idx];
                if (OUT_BF16) ((ushort*)Cp)[idx] = f2bf(v);
                else          ((float*)Cp)[idx]  = v;
            }
        }
    }
}

// ---------------- one-shot weight transpose+cast for all 14 weight matrices ----------------
struct PrepArgs {
    const float* src[14];
    ushort* dst[14];
    int K[14];
    int N[14];
};
__global__ void prep_all(PrepArgs pa, int total)
{
    int idx = blockIdx.x * 256 + threadIdx.x;
    if (idx >= total) return;
    int seg = 0, off = idx;
    while (off >= pa.K[seg] * pa.N[seg]) { off -= pa.K[seg] * pa.N[seg]; seg++; }
    int K = pa.K[seg], N = pa.N[seg];
    int n = off / K, k = off - n * K;
    pa.dst[seg][off] = f2bf(pa.src[seg][k * N + n]);
}

// ---------------- wave-per-row LN, f32 in/out (4 rows per block) ----------------
__global__ __launch_bounds__(256) void ln_wave(const float* __restrict__ in,
    const float* __restrict__ g, const float* __restrict__ b, float* __restrict__ out)
{
    int row = blockIdx.x * 4 + (threadIdx.x >> 6);
    int lane = threadIdx.x & 63;
    float4 x = *(const float4*)&in[(size_t)row * 256 + lane * 4];
    float m = waveSum(x.x + x.y + x.z + x.w) * (1.f / 256.f);
    float dx = x.x - m, dy = x.y - m, dz = x.z - m, dw = x.w - m;
    float v = waveSum(dx * dx + dy * dy + dz * dz + dw * dw) * (1.f / 256.f);
    float inv = 1.f / sqrtf(v + 1e-5f);
    float4 gg = *(const float4*)&g[lane * 4];
    float4 bbv = *(const float4*)&b[lane * 4];
    float4 o;
    o.x = dx * inv * gg.x + bbv.x; o.y = dy * inv * gg.y + bbv.y;
    o.z = dz * inv * gg.z + bbv.z; o.w = dw * inv * gg.w + bbv.w;
    *(float4*)&out[(size_t)row * 256 + lane * 4] = o;
}

// ---------------- wave-per-row double LN in place on bf16 buffer ----------------
__global__ __launch_bounds__(256) void ln2b_wave(ushort* __restrict__ buf,
    const float* __restrict__ g1, const float* __restrict__ b1,
    const float* __restrict__ g2, const float* __restrict__ b2)
{
    int row = blockIdx.x * 4 + (threadIdx.x >> 6);
    int lane = threadIdx.x & 63;
    ushort4 u = *(const ushort4*)&buf[(size_t)row * 256 + lane * 4];
    float x0 = bf2f(u.x), x1 = bf2f(u.y), x2 = bf2f(u.z), x3 = bf2f(u.w);
    float m = waveSum(x0 + x1 + x2 + x3) * (1.f / 256.f);
    float d0 = x0 - m, d1 = x1 - m, d2 = x2 - m, d3 = x3 - m;
    float v = waveSum(d0 * d0 + d1 * d1 + d2 * d2 + d3 * d3) * (1.f / 256.f);
    float inv = 1.f / sqrtf(v + 1e-5f);
    float4 gg = *(const float4*)&g1[lane * 4];
    float4 bbv = *(const float4*)&b1[lane * 4];
    float y0 = d0 * inv * gg.x + bbv.x, y1 = d1 * inv * gg.y + bbv.y;
    float y2 = d2 * inv * gg.z + bbv.z, y3 = d3 * inv * gg.w + bbv.w;
    float m2 = waveSum(y0 + y1 + y2 + y3) * (1.f / 256.f);
    float e0 = y0 - m2, e1 = y1 - m2, e2 = y2 - m2, e3 = y3 - m2;
    float v2 = waveSum(e0 * e0 + e1 * e1 + e2 * e2 + e3 * e3) * (1.f / 256.f);
    float inv2 = 1.f / sqrtf(v2 + 1e-5f);
    float4 g2v = *(const float4*)&g2[lane * 4];
    float4 b2v = *(const float4*)&b2[lane * 4];
    ushort4 o;
    o.x = f2bf(e0 * inv2 * g2v.x + b2v.x); o.y = f2bf(e1 * inv2 * g2v.y + b2v.y);
    o.z = f2bf(e2 * inv2 * g2v.z + b2v.z); o.w = f2bf(e3 * inv2 * g2v.w + b2v.w);
    *(ushort4*)&buf[(size_t)row * 256 + lane * 4] = o;
}

// ---------------- slots = mu + exp(log_sigma) * eps ----------------
__global__ void slots_init(const float* __restrict__ mu, const float* __restrict__ ls,
    const float* __restrict__ eps, float* __restrict__ slots)
{
    int idx = blockIdx.x * 256 + threadIdx.x;
    int md = idx % (TSs * Dd);
    slots[idx] = mu[md] + expf(ls[md]) * eps[idx];
}

// ---------------- dots[b,i,h,j] = (q . k) * 0.125 ; k is bf16 ----------------
__global__ __launch_bounds__(256) void dots_kernel(const float* __restrict__ qb,
    const ushort* __restrict__ kb, float* __restrict__ dots)
{
    int bid = blockIdx.x;
    int chunk = bid & 3, h = (bid >> 2) & 3, b = bid >> 4;
    int t = threadIdx.x, w = t >> 6, lane = t & 63;
    int j = chunk * 256 + w * 64 + lane;
    const uint* kp = (const uint*)(kb + (size_t)(b * Nn + j) * Dd + h * HDd);
    float kr[64];
    #pragma unroll
    for (int c = 0; c < 8; c++) {
        int4 kv4 = *(const int4*)(kp + c * 4);
        uint u0 = (uint)kv4.x, u1 = (uint)kv4.y, u2 = (uint)kv4.z, u3 = (uint)kv4.w;
        kr[c * 8 + 0] = __uint_as_float(u0 << 16); kr[c * 8 + 1] = __uint_as_float(u0 & 0xffff0000u);
        kr[c * 8 + 2] = __uint_as_float(u1 << 16); kr[c * 8 + 3] = __uint_as_float(u1 & 0xffff0000u);
        kr[c * 8 + 4] = __uint_as_float(u2 << 16); kr[c * 8 + 5] = __uint_as_float(u2 & 0xffff0000u);
        kr[c * 8 + 6] = __uint_as_float(u3 << 16); kr[c * 8 + 7] = __uint_as_float(u3 & 0xffff0000u);
    }
    const float* qbase = qb + b * TSs * Dd + h * HDd;
    #pragma unroll
    for (int i = 0; i < TSs; i++) {
        const float* qrow = qbase + i * Dd;
        float acc = 0.f;
        #pragma unroll
        for (int c = 0; c < 64; c++) acc += kr[c] * qrow[c];
        dots[(size_t)(b * 48 + i * 4 + h) * Nn + j] = acc * 0.125f;
    }
}

// ---------------- softmax over the 48 (i,h) entries per (b,j) ----------------
__global__ __launch_bounds__(256) void softmax48(float* __restrict__ dots)
{
    int b = blockIdx.x >> 2;
    int j = (blockIdx.x & 3) * 256 + threadIdx.x;
    float a[48];
    float m = -1e30f;
    #pragma unroll
    for (int idx = 0; idx < 48; idx++) { a[idx] = dots[(size_t)(b * 48 + idx) * Nn + j]; m = fmaxf(m, a[idx]); }
    float s = 0.f;
    #pragma unroll
    for (int idx = 0; idx < 48; idx++) { a[idx] = expf(a[idx] - m); s += a[idx]; }
    float inv = 1.f / s;
    #pragma unroll
    for (int idx = 0; idx < 48; idx++) dots[(size_t)(b * 48 + idx) * Nn + j] = a[idx] * inv;
}

// ---------------- updates with fused rowsum; 8 waves split j ----------------
__global__ __launch_bounds__(512) void updates_kernel(const float* __restrict__ attn,
    const ushort* __restrict__ vb, float* __restrict__ upd)
{
    int b = blockIdx.x >> 2, h = blockIdx.x & 3;
    int t = threadIdx.x, w = t >> 6, lane = t & 63;
    float acc[12] = {}, ra[12] = {};
    float accv = 0.f;
    for (int j = w; j < Nn; j += 8) {
        float vv = bf2f(vb[(size_t)(b * Nn + j) * Dd + h * HDd + lane]);
        accv += vv;
        #pragma unroll
        for (int i = 0; i < 12; i++) {
            float a = attn[(size_t)(b * 48 + i * 4 + h) * Nn + j];
            acc[i] += a * vv;
            ra[i]  += a;          // wave-uniform rowsum accumulation
        }
    }
    __shared__ float redA[8][12][64];
    __shared__ float redV[8][64];
    __shared__ float redR[8][12];
    #pragma unroll
    for (int i = 0; i < 12; i++) redA[w][i][lane] = acc[i];
    redV[w][lane] = accv;
    if (lane == 0) {
        #pragma unroll
        for (int i = 0; i < 12; i++) redR[w][i] = ra[i];
    }
    __syncthreads();
    if (w == 0) {
        float sv = 0.f;
        #pragma unroll
        for (int ww = 0; ww < 8; ww++) sv += redV[ww][lane];
        #pragma unroll
        for (int i = 0; i < 12; i++) {
            float s = 0.f, rs = 0.f;
            #pragma unroll
            for (int ww = 0; ww < 8; ww++) { s += redA[ww][i][lane]; rs += redR[ww][i]; }
            upd[(size_t)(b * TSs + i) * Dd + h * HDd + lane] = (s + 1e-8f * sv) / (rs + 1e-8f);
        }
    }
}

// ---------------- GRU gate combine ----------------
__global__ __launch_bounds__(256) void gru_gate(const float* __restrict__ gx,
    const float* __restrict__ gh, float* __restrict__ slots)
{
    int idx = blockIdx.x * 256 + threadIdx.x;
    int row = idx >> 8, col = idx & 255;
    int base = row * 768 + col;
    float xr = gx[base], xz = gx[base + 256], xnv = gx[base + 512];
    float hr = gh[base], hz = gh[base + 256], hn = gh[base + 512];
    float r = 1.f / (1.f + expf(-(xr + hr)));
    float z = 1.f / (1.f + expf(-(xz + hz)));
    float nv = tanhf(xnv + r * hn);
    float hp = slots[idx];
    slots[idx] = (1.f - z) * nv + z * hp;
}

// ---------------- selection head + masked x write ----------------
__global__ __launch_bounds__(256) void select_kernel(const float* __restrict__ slots,
    const float* __restrict__ w1, const float* __restrict__ b1,
    const float* __restrict__ w2, const float* __restrict__ b2,
    float* __restrict__ dec, float* __restrict__ xout)
{
    int b = blockIdx.x, t = threadIdx.x;
    __shared__ float t1[8][128];
    __shared__ float lg[8][2];
    __shared__ float dsh[8];
    const float* obj = slots + b * TSs * Dd;
    #pragma unroll
    for (int u = 0; u < 4; u++) {
        int idx = t + 256 * u;
        int k = idx >> 7, c = idx & 127;
        float s = b1[c];
        for (int d = 0; d < 256; d++) s += obj[k * 256 + d] * w1[d * 128 + c];
        t1[k][c] = fmaxf(s, 0.f);
    }
    __syncthreads();
    if (t < 16) {
        int k = t >> 1, o = t & 1;
        float s = b2[o];
        for (int c = 0; c < 128; c++) s += t1[k][c] * w2[c * 2 + o];
        lg[k][o] = s;
    }
    __syncthreads();
    if (t == 0) {
        float dv[8]; float sum = 0.f;
        for (int k = 0; k < 8; k++) { dv[k] = (lg[k][1] > lg[k][0]) ? 1.f : 0.f; sum += dv[k]; }
        float needed = fmaxf(2.f - sum, 0.f);
        float rank = 0.f;
        for (int k = 0; k < 8; k++) {
            float inact = 1.f - dv[k];
            rank += inact;
            if (inact > 0.f && rank <= needed) dv[k] = 1.f;
            dsh[k] = dv[k];
            dec[b * 8 + k] = dv[k];
        }
    }
    __syncthreads();
    for (int idx = t; idx < 2048; idx += 256) {
        int k = idx >> 8, c = idx & 255;
        xout[(b * 8 + k) * 256 + c] = obj[k * 256 + c] * dsh[k];
    }
}

// ---------------- GAT attention + residual ----------------
__global__ __launch_bounds__(256) void gat_attn(float* __restrict__ xb,
    const float* __restrict__ hmat, const float* __restrict__ av,
    const float* __restrict__ dec)
{
    int b = blockIdx.x, t = threadIdx.x;
    __shared__ float hs[8][256], xs[8][256];
    __shared__ float ei[8][4], ej[8][4], al[8][4][8], ds[8];
    for (int idx = t; idx < 2048; idx += 256) {
        int k = idx >> 8, c = idx & 255;
        hs[k][c] = hmat[(b * 8 + k) * 256 + c];
        xs[k][c] = xb[(b * 8 + k) * 256 + c];
    }
    if (t < 8) ds[t] = dec[b * 8 + t];
    __syncthreads();
    if (t < 32) {
        int k = t >> 2, h = t & 3;
        float s1 = 0.f, s2 = 0.f;
        for (int d = 0; d < 64; d++) {
            float hv = hs[k][h * 64 + d];
            s1 += hv * av[h * 128 + d];
            s2 += hv * av[h * 128 + 64 + d];
        }
        ei[k][h] = s1; ej[k][h] = s2;
    }
    __syncthreads();
    {
        int k = t >> 5, h = (t >> 3) & 3, n = t & 7;
        float e = ei[k][h] + ej[n][h];
        e = (e >= 0.f) ? e : 0.2f * e;
        if (ds[k] * ds[n] == 0.f) e = -1e9f;
        float mx = e;
        #pragma unroll
        for (int o = 4; o > 0; o >>= 1) mx = fmaxf(mx, __shfl_xor(mx, o, 8));
        float ex = expf(e - mx);
        float sm = ex;
        #pragma unroll
        for (int o = 4; o > 0; o >>= 1) sm += __shfl_xor(sm, o, 8);
        al[k][h][n] = ex / sm;
    }
    __syncthreads();
    int h = t >> 6, d = t & 63;
    for (int k = 0; k < 8; k++) {
        float o = 0.f;
        #pragma unroll
        for (int n = 0; n < 8; n++) o += al[k][h][n] * hs[n][h * 64 + d];
        xb[(b * 8 + k) * 256 + h * 64 + d] = xs[k][h * 64 + d] + o;
    }
}

// ======================================================================
extern "C" void kernel_launch(void* const* d_in, const int* in_sizes, int n_in,
                              void* d_out, int out_size, void* d_ws, size_t ws_size,
                              hipStream_t stream)
{
    (void)in_sizes; (void)n_in; (void)out_size; (void)ws_size;
    const float* features       = (const float*)d_in[0];
    const float* eps_noise      = (const float*)d_in[1];
    const float* in_w           = (const float*)d_in[2];
    const float* in_b           = (const float*)d_in[3];
    const float* in_ln_g        = (const float*)d_in[4];
    const float* in_ln_b        = (const float*)d_in[5];
    const float* ni_g           = (const float*)d_in[6];
    const float* ni_b           = (const float*)d_in[7];
    const float* slot_mu        = (const float*)d_in[8];
    const float* slot_log_sigma = (const float*)d_in[9];
    const float* q_w            = (const float*)d_in[10];
    const float* k_w            = (const float*)d_in[11];
    const float* v_w            = (const float*)d_in[12];
    const float* gru_wih        = (const float*)d_in[13];
    const float* gru_whh        = (const float*)d_in[14];
    const float* gru_bih        = (const float*)d_in[15];
    const float* gru_bhh        = (const float*)d_in[16];
    const float* ns_g           = (const float*)d_in[17];
    const float* ns_b           = (const float*)d_in[18];
    const float* ffn_ln_g       = (const float*)d_in[19];
    const float* ffn_ln_b       = (const float*)d_in[20];
    const float* ffn_w1         = (const float*)d_in[21];
    const float* ffn_b1         = (const float*)d_in[22];
    const float* ffn_w2         = (const float*)d_in[23];
    const float* ffn_b2         = (const float*)d_in[24];
    const float* sel_w1         = (const float*)d_in[25];
    const float* sel_b1         = (const float*)d_in[26];
    const float* sel_w2         = (const float*)d_in[27];
    const float* sel_b2         = (const float*)d_in[28];
    const float* gat_W          = (const float*)d_in[29];
    const float* gat_a          = (const float*)d_in[30];
    const float* gat_ln_g       = (const float*)d_in[31];
    const float* gat_ln_b       = (const float*)d_in[32];
    const float* gat_fln_g      = (const float*)d_in[33];
    const float* gat_fln_b      = (const float*)d_in[34];
    const float* gat_fw1        = (const float*)d_in[35];
    const float* gat_fb1        = (const float*)d_in[36];
    const float* gat_fw2        = (const float*)d_in[37];
    const float* gat_fb2        = (const float*)d_in[38];

    // ---- workspace layout ----
    ushort* kb  = (ushort*)d_ws;          // 16,777,216
    ushort* vb  = kb + 16777216;
    ushort* xnb = vb + 16777216;
    ushort* wtb = xnb + 16777216;         // 2,490,368 transposed bf16 weights
    ushort* h1b = wtb + 2490368;          // 786,432 (FFN/GAT hidden, bf16+gelu)
    float* fbase = (float*)(h1b + 786432);
    float* attn  = fbase;                 // 3,145,728
    float* gx    = attn;                  // alias (attn dead when GRU runs)
    float* gh    = attn + 589824;
    float* slots = attn + 3145728;        // 196,608
    float* sn    = slots + 196608;
    float* qbuf  = sn + 196608;
    float* upd   = qbuf + 196608;
    float* xb    = upd + 196608;          // 131,072
    float* hm    = xb + 131072;           // 131,072
    float* dec   = hm + 131072;           // 512

    // transposed weight offsets in wtb
    ushort* in_wT   = wtb;                 // 196608
    ushort* k_wT    = in_wT + 196608;      // 65536
    ushort* v_wT    = k_wT + 65536;
    ushort* q_wT    = v_wT + 65536;
    ushort* wihT    = q_wT + 65536;        // 196608
    ushort* whhT    = wihT + 196608;
    ushort* fw1T    = whhT + 196608;       // 262144
    ushort* fw2T    = fw1T + 262144;
    ushort* gW0T    = fw2T + 262144;       // 65536
    ushort* gW1T    = gW0T + 65536;
    ushort* gf1aT   = gW1T + 65536;        // 262144
    ushort* gf1bT   = gf1aT + 262144;
    ushort* gf2aT   = gf1bT + 262144;
    ushort* gf2bT   = gf2aT + 262144;

    dim3 blk(256);

    // 0) all weights -> bf16 [N][K] in one kernel
    PrepArgs pa;
    const float* srcs[14] = { in_w, k_w, v_w, q_w, gru_wih, gru_whh, ffn_w1, ffn_w2,
                              gat_W, gat_W + 65536, gat_fw1, gat_fw1 + 262144,
                              gat_fw2, gat_fw2 + 262144 };
    ushort* dsts[14] = { in_wT, k_wT, v_wT, q_wT, wihT, whhT, fw1T, fw2T,
                         gW0T, gW1T, gf1aT, gf1bT, gf2aT, gf2bT };
    int Ks[14] = { 768, 256, 256, 256, 256, 256, 256, 1024, 256, 256, 256, 256, 1024, 1024 };
    int Nsz[14] = { 256, 256, 256, 256, 768, 768, 1024, 256, 256, 256, 1024, 1024, 256, 256 };
    int total = 0;
    for (int s = 0; s < 14; s++) { pa.src[s] = srcs[s]; pa.dst[s] = dsts[s]; pa.K[s] = Ks[s]; pa.N[s] = Nsz[s]; total += Ks[s] * Nsz[s]; }
    prep_all<<<(total + 255) / 256, blk, 0, stream>>>(pa, total);

    // 1) xnb = bf16(features @ in_w + in_b); double-LN in place
    gemm_mfma<true, true, false, false><<<dim3(512, 1), blk, 0, stream>>>(
        features, in_wT, in_b, xnb, nullptr, Bb * Nn, 256, 768);
    ln2b_wave<<<Bb * Nn / 4, blk, 0, stream>>>(xnb, in_ln_g, in_ln_b, ni_g, ni_b);

    // 2) k, v projections (bf16 in/out)
    gemm_mfma<false, true, false, false><<<dim3(512, 1), blk, 0, stream>>>(
        xnb, k_wT, nullptr, kb, nullptr, Bb * Nn, 256, 256);
    gemm_mfma<false, true, false, false><<<dim3(512, 1), blk, 0, stream>>>(
        xnb, v_wT, nullptr, vb, nullptr, Bb * Nn, 256, 256);

    // 3) slots init
    slots_init<<<768, blk, 0, stream>>>(slot_mu, slot_log_sigma, eps_noise, slots);

    // 4) slot-attention iterations
    for (int it = 0; it < 3; it++) {
        ln_wave<<<192, blk, 0, stream>>>(slots, ns_g, ns_b, sn);
        gemm_mfma<true, false, false, false><<<dim3(6, 1), blk, 0, stream>>>(
            sn, q_wT, nullptr, qbuf, nullptr, 768, 256, 256);
        dots_kernel<<<Bb * Hh * 4, blk, 0, stream>>>(qbuf, kb, attn);
        softmax48<<<Bb * 4, blk, 0, stream>>>(attn);
        updates_kernel<<<Bb * Hh, dim3(512), 0, stream>>>(attn, vb, upd);
        gemm_mfma<true, false, false, false><<<dim3(6, 3), blk, 0, stream>>>(
            upd, wihT, gru_bih, gx, nullptr, 768, 768, 256);
        gemm_mfma<true, false, false, false><<<dim3(6, 3), blk, 0, stream>>>(
            slots, whhT, gru_bhh, gh, nullptr, 768, 768, 256);
        gru_gate<<<768, blk, 0, stream>>>(gx, gh, slots);
        ln_wave<<<192, blk, 0, stream>>>(slots, ffn_ln_g, ffn_ln_b, sn);
        gemm_mfma<true, true, true, false><<<dim3(6, 4), blk, 0, stream>>>(
            sn, fw1T, ffn_b1, h1b, nullptr, 768, 1024, 256);
        gemm_mfma<false, false, false, true><<<dim3(6, 1), blk, 0, stream>>>(
            h1b, fw2T, ffn_b2, slots, slots, 768, 256, 1024);
    }

    // 5) selection + masked x
    select_kernel<<<Bb, blk, 0, stream>>>(slots, sel_w1, sel_b1, sel_w2, sel_b2, dec, xb);

    // 6) GAT layers
    for (int l = 0; l < 2; l++) {
        ln_wave<<<128, blk, 0, stream>>>(xb, gat_ln_g + l * 256, gat_ln_b + l * 256, sn);
        gemm_mfma<true, false, false, false><<<dim3(4, 1), blk, 0, stream>>>(
            sn, l ? gW1T : gW0T, nullptr, hm, nullptr, 512, 256, 256);
        gat_attn<<<Bb, blk, 0, stream>>>(xb, hm, gat_a + l * 512, dec);
        ln_wave<<<128, blk, 0, stream>>>(xb, gat_fln_g + l * 256, gat_fln_b + l * 256, sn);
        gemm_mfma<true, true, true, false><<<dim3(4, 4), blk, 0, stream>>>(
            sn, l ? gf1bT : gf1aT, gat_fb1 + l * 1024, h1b, nullptr, 512, 1024, 256);
        gemm_mfma<false, false, false, true><<<dim3(4, 1), blk, 0, stream>>>(
            h1b, l ? gf2bT : gf2aT, gat_fb2 + l * 256,
            l ? (float*)d_out : xb, xb, 512, 256, 1024);
    }
}

// Round 4
// 881.136 us; speedup vs baseline: 2.2672x; 1.1367x over previous
//
#include <hip/hip_runtime.h>
#include <math.h>

// Problem constants
#define Bb 64
#define Nn 1024
#define FDd 768
#define Dd 256
#define KSs 8
#define TSs 12
#define Hh 4
#define HDd 64

typedef __attribute__((ext_vector_type(8))) short bf16x8;
typedef __attribute__((ext_vector_type(4))) float f32x4;

__device__ __forceinline__ ushort f2bf(float x) {
    union { float f; uint u; } v; v.f = x;
    uint r = v.u + 0x7FFFu + ((v.u >> 16) & 1u);   // RNE
    return (ushort)(r >> 16);
}
__device__ __forceinline__ float bf2f(ushort x) {
    union { uint u; float f; } v; v.u = ((uint)x) << 16;
    return v.f;
}
__device__ __forceinline__ uint pack2(float a, float b) {
    return (uint)f2bf(a) | ((uint)f2bf(b) << 16);
}
__device__ __forceinline__ float waveSum(float v) {
    #pragma unroll
    for (int o = 32; o > 0; o >>= 1) v += __shfl_xor(v, o);
    return v;
}
__device__ __forceinline__ float geluf(float v) {
    return 0.5f * v * (1.f + erff(v * 0.70710678118654752f));
}

// ---- skinny per-wave MFMA: 16-row A tile (LDS, lda=K+8) x B[N][K] (global bf16) ----
// D[m][n]: m = lk*4+r, n = n0+lr  (verified C/D layout)
template<int K>
__device__ __forceinline__ f32x4 mm16(const ushort* __restrict__ Alds,
    const ushort* __restrict__ Bg, int n0, int lr, int lk, f32x4 acc)
{
    const ushort* ar = Alds + lr * (K + 8) + lk * 8;
    const ushort* br = Bg + (size_t)(n0 + lr) * K + lk * 8;
    #pragma unroll
    for (int k0 = 0; k0 < K; k0 += 32)
        acc = __builtin_amdgcn_mfma_f32_16x16x32_bf16(
            *(const bf16x8*)(ar + k0), *(const bf16x8*)(br + k0), acc, 0, 0, 0);
    return acc;
}

// LN of a 256-wide f32 LDS row -> bf16 LDS row (one full wave participates)
__device__ __forceinline__ void ln_row_bf(const float* __restrict__ rowF,
    ushort* __restrict__ rowU, const float* __restrict__ g,
    const float* __restrict__ b, int lane)
{
    float4 x = *(const float4*)&rowF[lane * 4];
    float m = waveSum(x.x + x.y + x.z + x.w) * (1.f / 256.f);
    float d0 = x.x - m, d1 = x.y - m, d2 = x.z - m, d3 = x.w - m;
    float v = waveSum(d0 * d0 + d1 * d1 + d2 * d2 + d3 * d3) * (1.f / 256.f);
    float inv = 1.f / sqrtf(v + 1e-5f);
    float4 gg = *(const float4*)&g[lane * 4];
    float4 bb = *(const float4*)&b[lane * 4];
    ushort4 o;
    o.x = f2bf(d0 * inv * gg.x + bb.x); o.y = f2bf(d1 * inv * gg.y + bb.y);
    o.z = f2bf(d2 * inv * gg.z + bb.z); o.w = f2bf(d3 * inv * gg.w + bb.w);
    *(ushort4*)&rowU[lane * 4] = o;
}

// ============ big bf16 MFMA GEMM (in-proj / k / v): C[M][256] ============
#define LPAD 40
template<bool A_F32>
__global__ __launch_bounds__(256) void gemm_mfma(const void* __restrict__ Ap,
    const ushort* __restrict__ WT, const float* __restrict__ bias,
    ushort* __restrict__ C, int M, int K)
{
    __shared__ __align__(16) ushort As[128 * LPAD];
    __shared__ __align__(16) ushort Bs[256 * LPAD];
    const int t = threadIdx.x;
    const int m0 = blockIdx.x * 128;
    const int lane = t & 63, wv = t >> 6;
    const int wr = wv >> 1, wc = wv & 1;
    const int lr = lane & 15, lk = lane >> 4;

    f32x4 acc[4][8] = {};

    const float*  agf  = (const float*)Ap  + (size_t)(m0 + (t >> 1)) * K + (t & 1) * 16;
    const ushort* agb0 = (const ushort*)Ap + (size_t)(m0 + (t >> 2)) * K + (t & 3) * 8;
    const ushort* agb1 = (const ushort*)Ap + (size_t)(m0 + 64 + (t >> 2)) * K + (t & 3) * 8;
    const ushort* bg   = WT + (size_t)(t >> 2) * K + (t & 3) * 8;

    float4 fA0, fA1, fA2, fA3; int4 iA0, iA1; int4 iB0, iB1, iB2, iB3;

#define GLOAD(k0) do { \
        if (A_F32) { \
            fA0 = *(const float4*)(agf + (k0));      fA1 = *(const float4*)(agf + (k0) + 4); \
            fA2 = *(const float4*)(agf + (k0) + 8);  fA3 = *(const float4*)(agf + (k0) + 12); \
        } else { \
            iA0 = *(const int4*)(agb0 + (k0)); iA1 = *(const int4*)(agb1 + (k0)); \
        } \
        iB0 = *(const int4*)(bg + (k0)); \
        iB1 = *(const int4*)(bg + (size_t)64  * K + (k0)); \
        iB2 = *(const int4*)(bg + (size_t)128 * K + (k0)); \
        iB3 = *(const int4*)(bg + (size_t)192 * K + (k0)); \
    } while (0)

#define LSTORE() do { \
        if (A_F32) { \
            int4 w0, w1; \
            w0.x = pack2(fA0.x, fA0.y); w0.y = pack2(fA0.z, fA0.w); \
            w0.z = pack2(fA1.x, fA1.y); w0.w = pack2(fA1.z, fA1.w); \
            w1.x = pack2(fA2.x, fA2.y); w1.y = pack2(fA2.z, fA2.w); \
            w1.z = pack2(fA3.x, fA3.y); w1.w = pack2(fA3.z, fA3.w); \
            int base = (t >> 1) * LPAD + (t & 1) * 16; \
            *(int4*)&As[base] = w0; *(int4*)&As[base + 8] = w1; \
        } else { \
            *(int4*)&As[(t >> 2) * LPAD + (t & 3) * 8]        = iA0; \
            *(int4*)&As[(64 + (t >> 2)) * LPAD + (t & 3) * 8] = iA1; \
        } \
        *(int4*)&Bs[(t >> 2) * LPAD + (t & 3) * 8]         = iB0; \
        *(int4*)&Bs[(64 + (t >> 2)) * LPAD + (t & 3) * 8]  = iB1; \
        *(int4*)&Bs[(128 + (t >> 2)) * LPAD + (t & 3) * 8] = iB2; \
        *(int4*)&Bs[(192 + (t >> 2)) * LPAD + (t & 3) * 8] = iB3; \
    } while (0)

    GLOAD(0);
    for (int k0 = 0; k0 < K; k0 += 32) {
        LSTORE();
        __syncthreads();
        bf16x8 af[4], bfr[8];
        #pragma unroll
        for (int mi = 0; mi < 4; mi++)
            af[mi] = *(const bf16x8*)&As[(wr * 64 + mi * 16 + lr) * LPAD + lk * 8];
        #pragma unroll
        for (int ni = 0; ni < 8; ni++)
            bfr[ni] = *(const bf16x8*)&Bs[(wc * 128 + ni * 16 + lr) * LPAD + lk * 8];
        if (k0 + 32 < K) GLOAD(k0 + 32);
        #pragma unroll
        for (int mi = 0; mi < 4; mi++)
            #pragma unroll
            for (int ni = 0; ni < 8; ni++)
                acc[mi][ni] = __builtin_amdgcn_mfma_f32_16x16x32_bf16(af[mi], bfr[ni], acc[mi][ni], 0, 0, 0);
        __syncthreads();
    }
#undef GLOAD
#undef LSTORE
    #pragma unroll
    for (int mi = 0; mi < 4; mi++) {
        int grow = m0 + wr * 64 + mi * 16 + lk * 4;
        #pragma unroll
        for (int ni = 0; ni < 8; ni++) {
            int gcol = wc * 128 + ni * 16 + lr;
            float bv = bias ? bias[gcol] : 0.f;
            #pragma unroll
            for (int r = 0; r < 4; r++)
                C[(size_t)(grow + r) * 256 + gcol] = f2bf(acc[mi][ni][r] + bv);
        }
    }
}

// ---------------- one-shot weight transpose+cast (14 matrices) ----------------
struct PrepArgs {
    const float* src[14];
    ushort* dst[14];
    int K[14];
    int N[14];
};
__global__ void prep_all(PrepArgs pa, int total)
{
    int idx = blockIdx.x * 256 + threadIdx.x;
    if (idx >= total) return;
    int seg = 0, off = idx;
    while (off >= pa.K[seg] * pa.N[seg]) { off -= pa.K[seg] * pa.N[seg]; seg++; }
    int K = pa.K[seg], N = pa.N[seg];
    int n = off / K, k = off - n * K;
    pa.dst[seg][off] = f2bf(pa.src[seg][k * N + n]);
}

// ---------------- wave-per-row double LN in place on bf16 buffer ----------------
__global__ __launch_bounds__(256) void ln2b_wave(ushort* __restrict__ buf,
    const float* __restrict__ g1, const float* __restrict__ b1,
    const float* __restrict__ g2, const float* __restrict__ b2)
{
    int row = blockIdx.x * 4 + (threadIdx.x >> 6);
    int lane = threadIdx.x & 63;
    ushort4 u = *(const ushort4*)&buf[(size_t)row * 256 + lane * 4];
    float x0 = bf2f(u.x), x1 = bf2f(u.y), x2 = bf2f(u.z), x3 = bf2f(u.w);
    float m = waveSum(x0 + x1 + x2 + x3) * (1.f / 256.f);
    float d0 = x0 - m, d1 = x1 - m, d2 = x2 - m, d3 = x3 - m;
    float v = waveSum(d0 * d0 + d1 * d1 + d2 * d2 + d3 * d3) * (1.f / 256.f);
    float inv = 1.f / sqrtf(v + 1e-5f);
    float4 gg = *(const float4*)&g1[lane * 4];
    float4 bbv = *(const float4*)&b1[lane * 4];
    float y0 = d0 * inv * gg.x + bbv.x, y1 = d1 * inv * gg.y + bbv.y;
    float y2 = d2 * inv * gg.z + bbv.z, y3 = d3 * inv * gg.w + bbv.w;
    float m2 = waveSum(y0 + y1 + y2 + y3) * (1.f / 256.f);
    float e0 = y0 - m2, e1 = y1 - m2, e2 = y2 - m2, e3 = y3 - m2;
    float v2 = waveSum(e0 * e0 + e1 * e1 + e2 * e2 + e3 * e3) * (1.f / 256.f);
    float inv2 = 1.f / sqrtf(v2 + 1e-5f);
    float4 g2v = *(const float4*)&g2[lane * 4];
    float4 b2v = *(const float4*)&b2[lane * 4];
    ushort4 o;
    o.x = f2bf(e0 * inv2 * g2v.x + b2v.x); o.y = f2bf(e1 * inv2 * g2v.y + b2v.y);
    o.z = f2bf(e2 * inv2 * g2v.z + b2v.z); o.w = f2bf(e3 * inv2 * g2v.w + b2v.w);
    *(ushort4*)&buf[(size_t)row * 256 + lane * 4] = o;
}

// ---------------- slots init + LN + q (per batch) ----------------
__global__ __launch_bounds__(256) void slot_init_q(
    const float* __restrict__ mu, const float* __restrict__ ls,
    const float* __restrict__ eps, float* __restrict__ slots_g,
    float* __restrict__ qbuf, const ushort* __restrict__ qwT,
    const float* __restrict__ ns_g, const float* __restrict__ ns_b)
{
    __shared__ float sF[16 * 256];
    __shared__ __align__(16) ushort sU[16 * 264];
    int b = blockIdx.x, t = threadIdx.x;
    int lane = t & 63, wv = t >> 6, lr = lane & 15, lk = lane >> 4;
    for (int idx = t; idx < 4096; idx += 256) {
        int i = idx >> 8, c = idx & 255;
        float v = 0.f;
        if (i < 12) {
            int md = i * 256 + c;
            v = mu[md] + expf(ls[md]) * eps[(size_t)(b * 12 + i) * 256 + c];
            slots_g[(size_t)(b * 12 + i) * 256 + c] = v;
        }
        sF[idx] = v;
        sU[i * 264 + c] = 0;
    }
    __syncthreads();
    for (int rr = 0; rr < 3; rr++) {
        int row = wv * 3 + rr;
        ln_row_bf(sF + row * 256, sU + row * 264, ns_g, ns_b, lane);
    }
    __syncthreads();
    #pragma unroll
    for (int nt = 0; nt < 4; nt++) {
        f32x4 a = {0.f, 0.f, 0.f, 0.f};
        a = mm16<256>(sU, qwT, wv * 64 + nt * 16, lr, lk, a);
        int n = wv * 64 + nt * 16 + lr;
        #pragma unroll
        for (int r = 0; r < 4; r++) {
            int m = lk * 4 + r;
            if (m < 12) qbuf[(size_t)(b * 12 + m) * 256 + n] = a[r] * 0.125f;
        }
    }
}

// ---------------- fused dots + softmax48 ----------------
__global__ __launch_bounds__(256) void dots_softmax(const float* __restrict__ qb,
    const ushort* __restrict__ kb, float* __restrict__ attn)
{
    int b = blockIdx.x >> 2, chunk = blockIdx.x & 3;
    int t = threadIdx.x;
    int j = chunk * 256 + t;
    const float* qbase = qb + (size_t)b * 12 * 256;
    float a48[48];
    #pragma unroll
    for (int h = 0; h < 4; h++) {
        const uint* kp = (const uint*)(kb + (size_t)(b * Nn + j) * 256 + h * 64);
        float kr[64];
        #pragma unroll
        for (int c = 0; c < 8; c++) {
            int4 k4 = *(const int4*)(kp + c * 4);
            uint u0 = (uint)k4.x, u1 = (uint)k4.y, u2 = (uint)k4.z, u3 = (uint)k4.w;
            kr[c * 8 + 0] = __uint_as_float(u0 << 16); kr[c * 8 + 1] = __uint_as_float(u0 & 0xffff0000u);
            kr[c * 8 + 2] = __uint_as_float(u1 << 16); kr[c * 8 + 3] = __uint_as_float(u1 & 0xffff0000u);
            kr[c * 8 + 4] = __uint_as_float(u2 << 16); kr[c * 8 + 5] = __uint_as_float(u2 & 0xffff0000u);
            kr[c * 8 + 6] = __uint_as_float(u3 << 16); kr[c * 8 + 7] = __uint_as_float(u3 & 0xffff0000u);
        }
        #pragma unroll
        for (int i = 0; i < 12; i++) {
            const float* qr = qbase + i * 256 + h * 64;   // scale folded into q
            float acc = 0.f;
            #pragma unroll
            for (int c = 0; c < 64; c++) acc += kr[c] * qr[c];
            a48[i * 4 + h] = acc;
        }
    }
    float m = -1e30f;
    #pragma unroll
    for (int idx = 0; idx < 48; idx++) m = fmaxf(m, a48[idx]);
    float s = 0.f;
    #pragma unroll
    for (int idx = 0; idx < 48; idx++) { a48[idx] = expf(a48[idx] - m); s += a48[idx]; }
    float inv = 1.f / s;
    #pragma unroll
    for (int idx = 0; idx < 48; idx++)
        attn[(size_t)(b * 48 + idx) * Nn + j] = a48[idx] * inv;
}

// ---------------- updates with fused rowsum; 8 waves split j ----------------
__global__ __launch_bounds__(512) void updates_kernel(const float* __restrict__ attn,
    const ushort* __restrict__ vb, float* __restrict__ upd)
{
    int b = blockIdx.x >> 2, h = blockIdx.x & 3;
    int t = threadIdx.x, w = t >> 6, lane = t & 63;
    float acc[12] = {}, ra[12] = {};
    float accv = 0.f;
    for (int j = w; j < Nn; j += 8) {
        float vv = bf2f(vb[(size_t)(b * Nn + j) * Dd + h * HDd + lane]);
        accv += vv;
        #pragma unroll
        for (int i = 0; i < 12; i++) {
            float a = attn[(size_t)(b * 48 + i * 4 + h) * Nn + j];
            acc[i] += a * vv;
            ra[i]  += a;
        }
    }
    __shared__ float redA[8][12][64];
    __shared__ float redV[8][64];
    __shared__ float redR[8][12];
    #pragma unroll
    for (int i = 0; i < 12; i++) redA[w][i][lane] = acc[i];
    redV[w][lane] = accv;
    if (lane == 0) {
        #pragma unroll
        for (int i = 0; i < 12; i++) redR[w][i] = ra[i];
    }
    __syncthreads();
    if (w == 0) {
        float sv = 0.f;
        #pragma unroll
        for (int ww = 0; ww < 8; ww++) sv += redV[ww][lane];
        #pragma unroll
        for (int i = 0; i < 12; i++) {
            float s = 0.f, rs = 0.f;
            #pragma unroll
            for (int ww = 0; ww < 8; ww++) { s += redA[ww][i][lane]; rs += redR[ww][i]; }
            upd[(size_t)(b * TSs + i) * Dd + h * HDd + lane] = (s + 1e-8f * sv) / (rs + 1e-8f);
        }
    }
}

// ---------------- fused GRU + gate + FFN + (LN+q) per batch ----------------
// dyn smem: gB f32[2*16*768] (98304B, hS ushort[16*1032] aliases) | sF f32[16*256] | sU,sS ushort[16*264]
#define SLOT_SMEM (98304 + 16384 + 2 * 16 * 264 * 2)
__global__ __launch_bounds__(256) void slot_step(
    const float* __restrict__ upd, float* __restrict__ slots_g,
    float* __restrict__ qbuf,
    const ushort* __restrict__ wihT, const ushort* __restrict__ whhT,
    const ushort* __restrict__ fw1T, const ushort* __restrict__ fw2T,
    const ushort* __restrict__ qwT,
    const float* __restrict__ bih, const float* __restrict__ bhh,
    const float* __restrict__ fln_g, const float* __restrict__ fln_b,
    const float* __restrict__ f_b1, const float* __restrict__ f_b2,
    const float* __restrict__ ns_g, const float* __restrict__ ns_b, int doQ)
{
    extern __shared__ __align__(16) char smem[];
    float*  gB = (float*)smem;                       // gx at 0, gh at 12288 floats
    ushort* hS = (ushort*)smem;                      // [16][1032] aliases gB
    float*  sF = (float*)(smem + 98304);
    ushort* sU = (ushort*)(smem + 98304 + 16384);
    ushort* sS = sU + 16 * 264;

    int b = blockIdx.x, t = threadIdx.x;
    int lane = t & 63, wv = t >> 6, lr = lane & 15, lk = lane >> 4;

    for (int idx = t; idx < 4096; idx += 256) {
        int i = idx >> 8, c = idx & 255;
        float uv = 0.f, sv = 0.f;
        if (i < 12) {
            uv = upd[(size_t)(b * 12 + i) * 256 + c];
            sv = slots_g[(size_t)(b * 12 + i) * 256 + c];
        }
        sU[i * 264 + c] = f2bf(uv);
        sS[i * 264 + c] = f2bf(sv);
        sF[idx] = sv;
    }
    __syncthreads();
    // GRU matmuls: gx = upd@wih + bih ; gh = slots@whh + bhh
    {
        int n0w = wv * 192;
        #pragma unroll
        for (int nt = 0; nt < 12; nt++) {
            f32x4 z = {0.f, 0.f, 0.f, 0.f};
            f32x4 ax = mm16<256>(sU, wihT, n0w + nt * 16, lr, lk, z);
            f32x4 ah = mm16<256>(sS, whhT, n0w + nt * 16, lr, lk, z);
            int n = n0w + nt * 16 + lr;
            float bx = bih[n], bh = bhh[n];
            #pragma unroll
            for (int r = 0; r < 4; r++) {
                int m = lk * 4 + r;
                gB[m * 768 + n] = ax[r] + bx;
                gB[12288 + m * 768 + n] = ah[r] + bh;
            }
        }
    }
    __syncthreads();
    // gate -> sF (new slots)
    #pragma unroll
    for (int i = 0; i < 12; i++) {
        float xr = gB[i * 768 + t], xz = gB[i * 768 + 256 + t], xn = gB[i * 768 + 512 + t];
        float hr = gB[12288 + i * 768 + t], hz = gB[12288 + i * 768 + 256 + t], hn = gB[12288 + i * 768 + 512 + t];
        float r = 1.f / (1.f + expf(-(xr + hr)));
        float z = 1.f / (1.f + expf(-(xz + hz)));
        float nv = tanhf(xn + r * hn);
        float hp = sF[i * 256 + t];
        sF[i * 256 + t] = (1.f - z) * nv + z * hp;
    }
    __syncthreads();
    // ffn LN -> sU
    for (int rr = 0; rr < 3; rr++) {
        int row = wv * 3 + rr;
        ln_row_bf(sF + row * 256, sU + row * 264, fln_g, fln_b, lane);
    }
    __syncthreads();
    // FFN1 + gelu -> hS (overwrites gB region; gx/gh dead)
    #pragma unroll
    for (int nt = 0; nt < 16; nt++) {
        f32x4 a = {0.f, 0.f, 0.f, 0.f};
        a = mm16<256>(sU, fw1T, wv * 256 + nt * 16, lr, lk, a);
        int n = wv * 256 + nt * 16 + lr;
        float bv = f_b1[n];
        #pragma unroll
        for (int r = 0; r < 4; r++)
            hS[(lk * 4 + r) * 1032 + n] = f2bf(geluf(a[r] + bv));
    }
    __syncthreads();
    // FFN2 + bias + residual -> sF, slots_g
    #pragma unroll
    for (int nt = 0; nt < 4; nt++) {
        f32x4 a = {0.f, 0.f, 0.f, 0.f};
        a = mm16<1024>(hS, fw2T, wv * 64 + nt * 16, lr, lk, a);
        int n = wv * 64 + nt * 16 + lr;
        float bv = f_b2[n];
        #pragma unroll
        for (int r = 0; r < 4; r++) {
            int m = lk * 4 + r;
            if (m < 12) {
                float out = a[r] + bv + sF[m * 256 + n];
                sF[m * 256 + n] = out;
                slots_g[(size_t)(b * 12 + m) * 256 + n] = out;
            }
        }
    }
    if (doQ) {
        __syncthreads();
        for (int rr = 0; rr < 3; rr++) {
            int row = wv * 3 + rr;
            ln_row_bf(sF + row * 256, sU + row * 264, ns_g, ns_b, lane);
        }
        __syncthreads();
        #pragma unroll
        for (int nt = 0; nt < 4; nt++) {
            f32x4 a = {0.f, 0.f, 0.f, 0.f};
            a = mm16<256>(sU, qwT, wv * 64 + nt * 16, lr, lk, a);
            int n = wv * 64 + nt * 16 + lr;
            #pragma unroll
            for (int r = 0; r < 4; r++) {
                int m = lk * 4 + r;
                if (m < 12) qbuf[(size_t)(b * 12 + m) * 256 + n] = a[r] * 0.125f;
            }
        }
    }
}

// ---------------- selection head + masked x write ----------------
__global__ __launch_bounds__(256) void select_kernel(const float* __restrict__ slots,
    const float* __restrict__ w1, const float* __restrict__ b1,
    const float* __restrict__ w2, const float* __restrict__ b2,
    float* __restrict__ dec, float* __restrict__ xout)
{
    int b = blockIdx.x, t = threadIdx.x;
    __shared__ float t1[8][128];
    __shared__ float lg[8][2];
    __shared__ float dsh[8];
    const float* obj = slots + (size_t)b * TSs * Dd;
    #pragma unroll
    for (int u = 0; u < 4; u++) {
        int idx = t + 256 * u;
        int k = idx >> 7, c = idx & 127;
        float s = b1[c];
        for (int d = 0; d < 256; d++) s += obj[k * 256 + d] * w1[d * 128 + c];
        t1[k][c] = fmaxf(s, 0.f);
    }
    __syncthreads();
    if (t < 16) {
        int k = t >> 1, o = t & 1;
        float s = b2[o];
        for (int c = 0; c < 128; c++) s += t1[k][c] * w2[c * 2 + o];
        lg[k][o] = s;
    }
    __syncthreads();
    if (t == 0) {
        float dv[8]; float sum = 0.f;
        for (int k = 0; k < 8; k++) { dv[k] = (lg[k][1] > lg[k][0]) ? 1.f : 0.f; sum += dv[k]; }
        float needed = fmaxf(2.f - sum, 0.f);
        float rank = 0.f;
        for (int k = 0; k < 8; k++) {
            float inact = 1.f - dv[k];
            rank += inact;
            if (inact > 0.f && rank <= needed) dv[k] = 1.f;
            dsh[k] = dv[k];
            dec[b * 8 + k] = dv[k];
        }
    }
    __syncthreads();
    for (int idx = t; idx < 2048; idx += 256) {
        int k = idx >> 8, c = idx & 255;
        xout[(size_t)(b * 8 + k) * 256 + c] = obj[k * 256 + c] * dsh[k];
    }
}

// ---------------- fused GAT layer per batch ----------------
// dyn smem: xF f32[16*256] | hmF f32[8*256] | sU ushort[16*264] | hS ushort[16*1032]
#define GAT_SMEM (16384 + 8192 + 8448 + 33024)
__global__ __launch_bounds__(256) void gat_fused(
    const float* __restrict__ xin, float* __restrict__ xout,
    const float* __restrict__ dec,
    const ushort* __restrict__ gWT, const ushort* __restrict__ gf1T,
    const ushort* __restrict__ gf2T, const float* __restrict__ av,
    const float* __restrict__ lng, const float* __restrict__ lnb,
    const float* __restrict__ flng, const float* __restrict__ flnb,
    const float* __restrict__ fb1, const float* __restrict__ fb2)
{
    extern __shared__ __align__(16) char smem[];
    float*  xF  = (float*)smem;
    float*  hmF = (float*)(smem + 16384);
    ushort* sU  = (ushort*)(smem + 16384 + 8192);
    ushort* hS  = (ushort*)(smem + 16384 + 8192 + 8448);
    __shared__ float ei[8][4], ej[8][4], al[8][4][8], ds[8];

    int b = blockIdx.x, t = threadIdx.x;
    int lane = t & 63, wv = t >> 6, lr = lane & 15, lk = lane >> 4;

    for (int idx = t; idx < 4096; idx += 256) {
        int k = idx >> 8, c = idx & 255;
        xF[idx] = (k < 8) ? xin[(size_t)(b * 8 + k) * 256 + c] : 0.f;
        sU[k * 264 + c] = 0;
    }
    if (t < 8) ds[t] = dec[b * 8 + t];
    __syncthreads();
    for (int rr = 0; rr < 2; rr++) {
        int row = wv + rr * 4;
        ln_row_bf(xF + row * 256, sU + row * 264, lng, lnb, lane);
    }
    __syncthreads();
    // hm = LN(x) @ gat_W
    #pragma unroll
    for (int nt = 0; nt < 4; nt++) {
        f32x4 a = {0.f, 0.f, 0.f, 0.f};
        a = mm16<256>(sU, gWT, wv * 64 + nt * 16, lr, lk, a);
        int n = wv * 64 + nt * 16 + lr;
        #pragma unroll
        for (int r = 0; r < 4; r++) {
            int m = lk * 4 + r;
            if (m < 8) hmF[m * 256 + n] = a[r];
        }
    }
    __syncthreads();
    if (t < 32) {
        int k = t >> 2, h = t & 3;
        float s1 = 0.f, s2 = 0.f;
        for (int d = 0; d < 64; d++) {
            float hv = hmF[k * 256 + h * 64 + d];
            s1 += hv * av[h * 128 + d];
            s2 += hv * av[h * 128 + 64 + d];
        }
        ei[k][h] = s1; ej[k][h] = s2;
    }
    __syncthreads();
    {
        int k = t >> 5, h = (t >> 3) & 3, n = t & 7;
        float e = ei[k][h] + ej[n][h];
        e = (e >= 0.f) ? e : 0.2f * e;
        if (ds[k] * ds[n] == 0.f) e = -1e9f;
        float mx = e;
        #pragma unroll
        for (int o = 4; o > 0; o >>= 1) mx = fmaxf(mx, __shfl_xor(mx, o, 8));
        float ex = expf(e - mx);
        float sm = ex;
        #pragma unroll
        for (int o = 4; o > 0; o >>= 1) sm += __shfl_xor(sm, o, 8);
        al[k][h][n] = ex / sm;
    }
    __syncthreads();
    {
        int h = t >> 6, d = t & 63;
        #pragma unroll
        for (int k = 0; k < 8; k++) {
            float o = 0.f;
            #pragma unroll
            for (int n = 0; n < 8; n++) o += al[k][h][n] * hmF[n * 256 + h * 64 + d];
            xF[k * 256 + h * 64 + d] += o;   // y = x + out
        }
    }
    __syncthreads();
    for (int rr = 0; rr < 2; rr++) {
        int row = wv + rr * 4;
        ln_row_bf(xF + row * 256, sU + row * 264, flng, flnb, lane);
    }
    __syncthreads();
    #pragma unroll
    for (int nt = 0; nt < 16; nt++) {
        f32x4 a = {0.f, 0.f, 0.f, 0.f};
        a = mm16<256>(sU, gf1T, wv * 256 + nt * 16, lr, lk, a);
        int n = wv * 256 + nt * 16 + lr;
        float bv = fb1[n];
        #pragma unroll
        for (int r = 0; r < 4; r++)
            hS[(lk * 4 + r) * 1032 + n] = f2bf(geluf(a[r] + bv));
    }
    __syncthreads();
    #pragma unroll
    for (int nt = 0; nt < 4; nt++) {
        f32x4 a = {0.f, 0.f, 0.f, 0.f};
        a = mm16<1024>(hS, gf2T, wv * 64 + nt * 16, lr, lk, a);
        int n = wv * 64 + nt * 16 + lr;
        float bv = fb2[n];
        #pragma unroll
        for (int r = 0; r < 4; r++) {
            int m = lk * 4 + r;
            if (m < 8) xout[(size_t)(b * 8 + m) * 256 + n] = xF[m * 256 + n] + a[r] + bv;
        }
    }
}

// ======================================================================
extern "C" void kernel_launch(void* const* d_in, const int* in_sizes, int n_in,
                              void* d_out, int out_size, void* d_ws, size_t ws_size,
                              hipStream_t stream)
{
    (void)in_sizes; (void)n_in; (void)out_size; (void)ws_size;
    const float* features       = (const float*)d_in[0];
    const float* eps_noise      = (const float*)d_in[1];
    const float* in_w           = (const float*)d_in[2];
    const float* in_b           = (const float*)d_in[3];
    const float* in_ln_g        = (const float*)d_in[4];
    const float* in_ln_b        = (const float*)d_in[5];
    const float* ni_g           = (const float*)d_in[6];
    const float* ni_b           = (const float*)d_in[7];
    const float* slot_mu        = (const float*)d_in[8];
    const float* slot_log_sigma = (const float*)d_in[9];
    const float* q_w            = (const float*)d_in[10];
    const float* k_w            = (const float*)d_in[11];
    const float* v_w            = (const float*)d_in[12];
    const float* gru_wih        = (const float*)d_in[13];
    const float* gru_whh        = (const float*)d_in[14];
    const float* gru_bih        = (const float*)d_in[15];
    const float* gru_bhh        = (const float*)d_in[16];
    const float* ns_g           = (const float*)d_in[17];
    const float* ns_b           = (const float*)d_in[18];
    const float* ffn_ln_g       = (const float*)d_in[19];
    const float* ffn_ln_b       = (const float*)d_in[20];
    const float* ffn_w1         = (const float*)d_in[21];
    const float* ffn_b1         = (const float*)d_in[22];
    const float* ffn_w2         = (const float*)d_in[23];
    const float* ffn_b2         = (const float*)d_in[24];
    const float* sel_w1         = (const float*)d_in[25];
    const float* sel_b1         = (const float*)d_in[26];
    const float* sel_w2         = (const float*)d_in[27];
    const float* sel_b2         = (const float*)d_in[28];
    const float* gat_W          = (const float*)d_in[29];
    const float* gat_a          = (const float*)d_in[30];
    const float* gat_ln_g       = (const float*)d_in[31];
    const float* gat_ln_b       = (const float*)d_in[32];
    const float* gat_fln_g      = (const float*)d_in[33];
    const float* gat_fln_b      = (const float*)d_in[34];
    const float* gat_fw1        = (const float*)d_in[35];
    const float* gat_fb1        = (const float*)d_in[36];
    const float* gat_fw2        = (const float*)d_in[37];
    const float* gat_fb2        = (const float*)d_in[38];

    // ---- workspace layout ----
    ushort* kb  = (ushort*)d_ws;
    ushort* vb  = kb + 16777216;
    ushort* xnb = vb + 16777216;
    ushort* wtb = xnb + 16777216;         // 2,490,368 transposed bf16 weights
    float* fbase = (float*)(wtb + 2490368);
    float* attn  = fbase;                 // 3,145,728
    float* slots = attn + 3145728;        // 196,608
    float* qbuf  = slots + 196608;        // 196,608
    float* upd   = qbuf + 196608;         // 196,608
    float* xb    = upd + 196608;          // 131,072
    float* dec   = xb + 131072;           // 512

    ushort* in_wT = wtb;                  // 196608
    ushort* k_wT  = in_wT + 196608;       // 65536
    ushort* v_wT  = k_wT + 65536;
    ushort* q_wT  = v_wT + 65536;
    ushort* wihT  = q_wT + 65536;         // 196608
    ushort* whhT  = wihT + 196608;
    ushort* fw1T  = whhT + 196608;        // 262144
    ushort* fw2T  = fw1T + 262144;
    ushort* gW0T  = fw2T + 262144;        // 65536
    ushort* gW1T  = gW0T + 65536;
    ushort* gf1aT = gW1T + 65536;         // 262144
    ushort* gf1bT = gf1aT + 262144;
    ushort* gf2aT = gf1bT + 262144;
    ushort* gf2bT = gf2aT + 262144;

    dim3 blk(256);

    // 0) all weights -> bf16 [N][K]
    PrepArgs pa;
    const float* srcs[14] = { in_w, k_w, v_w, q_w, gru_wih, gru_whh, ffn_w1, ffn_w2,
                              gat_W, gat_W + 65536, gat_fw1, gat_fw1 + 262144,
                              gat_fw2, gat_fw2 + 262144 };
    ushort* dsts[14] = { in_wT, k_wT, v_wT, q_wT, wihT, whhT, fw1T, fw2T,
                         gW0T, gW1T, gf1aT, gf1bT, gf2aT, gf2bT };
    int Ks[14]  = { 768, 256, 256, 256, 256, 256, 256, 1024, 256, 256, 256, 256, 1024, 1024 };
    int Nsz[14] = { 256, 256, 256, 256, 768, 768, 1024, 256, 256, 256, 1024, 1024, 256, 256 };
    int total = 0;
    for (int s = 0; s < 14; s++) { pa.src[s] = srcs[s]; pa.dst[s] = dsts[s]; pa.K[s] = Ks[s]; pa.N[s] = Nsz[s]; total += Ks[s] * Nsz[s]; }
    prep_all<<<(total + 255) / 256, blk, 0, stream>>>(pa, total);

    // 1) xnb = bf16(features @ in_w + in_b); double-LN in place
    gemm_mfma<true><<<512, blk, 0, stream>>>(features, in_wT, in_b, xnb, Bb * Nn, 768);
    ln2b_wave<<<Bb * Nn / 4, blk, 0, stream>>>(xnb, in_ln_g, in_ln_b, ni_g, ni_b);

    // 2) k, v projections
    gemm_mfma<false><<<512, blk, 0, stream>>>(xnb, k_wT, nullptr, kb, Bb * Nn, 256);
    gemm_mfma<false><<<512, blk, 0, stream>>>(xnb, v_wT, nullptr, vb, Bb * Nn, 256);

    // 3) slots init + first q
    slot_init_q<<<Bb, blk, 0, stream>>>(slot_mu, slot_log_sigma, eps_noise,
                                        slots, qbuf, q_wT, ns_g, ns_b);

    // 4) slot-attention iterations (3 launches per iter)
    for (int it = 0; it < 3; it++) {
        dots_softmax<<<Bb * 4, blk, 0, stream>>>(qbuf, kb, attn);
        updates_kernel<<<Bb * Hh, dim3(512), 0, stream>>>(attn, vb, upd);
        slot_step<<<Bb, blk, SLOT_SMEM, stream>>>(upd, slots, qbuf,
            wihT, whhT, fw1T, fw2T, q_wT, gru_bih, gru_bhh,
            ffn_ln_g, ffn_ln_b, ffn_b1, ffn_b2, ns_g, ns_b, (it < 2) ? 1 : 0);
    }

    // 5) selection + masked x
    select_kernel<<<Bb, blk, 0, stream>>>(slots, sel_w1, sel_b1, sel_w2, sel_b2, dec, xb);

    // 6) GAT layers (one fused kernel each)
    gat_fused<<<Bb, blk, GAT_SMEM, stream>>>(xb, xb, dec, gW0T, gf1aT, gf2aT,
        gat_a, gat_ln_g, gat_ln_b, gat_fln_g, gat_fln_b, gat_fb1, gat_fb2);
    gat_fused<<<Bb, blk, GAT_SMEM, stream>>>(xb, (float*)d_out, dec, gW1T, gf1bT, gf2bT,
        gat_a + 512, gat_ln_g + 256, gat_ln_b + 256, gat_fln_g + 256, gat_fln_b + 256,
        gat_fb1 + 1024, gat_fb2 + 256);
}